// Round 1
// baseline (555.969 us; speedup 1.0000x reference)
//
#include <hip/hip_runtime.h>
#include <hip/hip_bf16.h>
#include <math.h>

typedef __attribute__((ext_vector_type(4))) float f32x4;
typedef __attribute__((ext_vector_type(8))) short bf16x8;

#define LDSP(p)  ((__attribute__((address_space(3))) void*)(p))
#define GMEMP(p) ((const __attribute__((address_space(1))) void*)(p))

__device__ __forceinline__ short f2b(float f) {
  __hip_bfloat16 h = __float2bfloat16(f);
  return __builtin_bit_cast(short, h);
}
__device__ __forceinline__ float b2f(short s) {
  __hip_bfloat16 h = __builtin_bit_cast(__hip_bfloat16, s);
  return __bfloat162float(h);
}

// ---------------- elementwise f32 -> bf16 (8 elems/thread) ----------------
__global__ void cvt_kernel(const float* __restrict__ src, short* __restrict__ dst, int n8) {
  int i = blockIdx.x * blockDim.x + threadIdx.x;
  if (i >= n8) return;
  const float4* s4 = (const float4*)src;
  float4 a = s4[2 * i], b = s4[2 * i + 1];
  bf16x8 o;
  o[0] = f2b(a.x); o[1] = f2b(a.y); o[2] = f2b(a.z); o[3] = f2b(a.w);
  o[4] = f2b(b.x); o[5] = f2b(b.y); o[6] = f2b(b.z); o[7] = f2b(b.w);
  *(bf16x8*)(dst + (size_t)i * 8) = o;
}

// ---------------- f32 [rows][cols] -> bf16 [cols][rows] -------------------
__global__ void transpose_kernel(const float* __restrict__ src, short* __restrict__ dst,
                                 int rows, int cols) {
  __shared__ float tile[32][33];
  int c0 = blockIdx.x * 32, r0 = blockIdx.y * 32;
  int tx = threadIdx.x & 31, ty = threadIdx.x >> 5;  // 256 thr = 32 x 8
  for (int i = ty; i < 32; i += 8)
    tile[i][tx] = src[(size_t)(r0 + i) * cols + c0 + tx];
  __syncthreads();
  for (int i = ty; i < 32; i += 8)
    dst[(size_t)(c0 + i) * rows + r0 + tx] = f2b(tile[tx][i]);
}

// ---------------- bf16 GEMM: C = A[M][K] @ B[K][N], Bt = B^T [N][K] -------
// 128x128 tile, BK=32, 4 waves (2x2), each wave 64x64 = 4x4 16x16 frags.
template <int OUTBF>
__global__ __launch_bounds__(256) void gemm_bt(const short* __restrict__ A,
                                               const short* __restrict__ Bt,
                                               void* __restrict__ Cv,
                                               int M, int N, int K) {
  __shared__ alignas(16) short As[128 * 32];
  __shared__ alignas(16) short Bs[128 * 32];
  const int m0 = blockIdx.y * 128, n0 = blockIdx.x * 128;
  const int wave = threadIdx.x >> 6, lane = threadIdx.x & 63;
  const int g = lane >> 4, cl = lane & 15;
  const int wr = (wave >> 1) * 64, wc = (wave & 1) * 64;
  f32x4 acc[4][4];
#pragma unroll
  for (int i = 0; i < 4; ++i)
#pragma unroll
    for (int j = 0; j < 4; ++j) acc[i][j] = (f32x4){0.f, 0.f, 0.f, 0.f};

  const size_t lda = (size_t)K;
  for (int kt = 0; kt < K; kt += 32) {
#pragma unroll
    for (int c = 0; c < 2; ++c) {
      int e = (wave * 2 + c) * 512;          // uniform per wave (shorts)
      int el = e + lane * 8;                 // this lane's element
      const short* ga = A + (size_t)(m0 + (el >> 5)) * lda + kt + (el & 31);
      __builtin_amdgcn_global_load_lds(GMEMP(ga), LDSP(&As[e]), 16, 0, 0);
      const short* gb = Bt + (size_t)(n0 + (el >> 5)) * lda + kt + (el & 31);
      __builtin_amdgcn_global_load_lds(GMEMP(gb), LDSP(&Bs[e]), 16, 0, 0);
    }
    __syncthreads();
    bf16x8 af[4], bfr[4];
#pragma unroll
    for (int i = 0; i < 4; ++i)
      af[i] = *(const bf16x8*)&As[(wr + 16 * i + cl) * 32 + 8 * g];
#pragma unroll
    for (int j = 0; j < 4; ++j)
      bfr[j] = *(const bf16x8*)&Bs[(wc + 16 * j + cl) * 32 + 8 * g];
#pragma unroll
    for (int i = 0; i < 4; ++i)
#pragma unroll
      for (int j = 0; j < 4; ++j)
        acc[i][j] = __builtin_amdgcn_mfma_f32_16x16x32_bf16(af[i], bfr[j], acc[i][j], 0, 0, 0);
    __syncthreads();
  }
#pragma unroll
  for (int i = 0; i < 4; ++i)
#pragma unroll
    for (int j = 0; j < 4; ++j)
#pragma unroll
      for (int r = 0; r < 4; ++r) {
        int row = m0 + wr + 16 * i + 4 * g + r;
        int col = n0 + wc + 16 * j + cl;
        if (OUTBF)
          ((short*)Cv)[(size_t)row * N + col] = f2b(acc[i][j][r]);
        else
          ((float*)Cv)[(size_t)row * N + col] = acc[i][j][r];
      }
}

// ---------------- RoPE on q: qkv[row][h*128+2i..] -> q_bf[b][h][t][..] ----
__global__ void rope_q_kernel(const short* __restrict__ qkv, short* __restrict__ qb) {
  int tid = blockIdx.x * 256 + threadIdx.x;  // B*T*H*64 = 4194304
  int i = tid & 63;
  int h = (tid >> 6) & 15;
  int row = tid >> 10;  // b*2048 + t
  int t = row & 2047;
  int b = row >> 11;
  unsigned u = *(const unsigned*)(qkv + (size_t)row * 3072 + h * 128 + 2 * i);
  float x1 = b2f((short)(u & 0xffff));
  float x2 = b2f((short)(u >> 16));
  float inv = powf(10000.0f, -(float)i * (1.0f / 64.0f));
  float ang = (float)t * inv;
  float sn, cs;
  sincosf(ang, &sn, &cs);
  float o1 = x1 * cs - x2 * sn;
  float o2 = x1 * sn + x2 * cs;
  unsigned w = (unsigned)(unsigned short)f2b(o1) | ((unsigned)(unsigned short)f2b(o2) << 16);
  *(unsigned*)(qb + (size_t)((b * 16 + h) * 2048 + t) * 128 + 2 * i) = w;
}

// ---------------- RoPE on k + window select -> k_sel[b][kv][1152][128] ----
__global__ void rope_k_kernel(const short* __restrict__ qkv, short* __restrict__ ksel) {
  int tid = blockIdx.x * 256 + threadIdx.x;  // B*T*KV*64 = 1048576
  int i = tid & 63;
  int kvh = (tid >> 6) & 3;
  int row = tid >> 8;
  int t = row & 2047;
  int b = row >> 11;
  int idx = t < 128 ? t : (t >= 1024 ? t - 896 : -1);
  if (idx < 0) return;
  unsigned u = *(const unsigned*)(qkv + (size_t)row * 3072 + 2048 + kvh * 128 + 2 * i);
  float x1 = b2f((short)(u & 0xffff));
  float x2 = b2f((short)(u >> 16));
  float inv = powf(10000.0f, -(float)i * (1.0f / 64.0f));
  float ang = (float)t * inv;
  float sn, cs;
  sincosf(ang, &sn, &cs);
  float o1 = x1 * cs - x2 * sn;
  float o2 = x1 * sn + x2 * cs;
  unsigned w = (unsigned)(unsigned short)f2b(o1) | ((unsigned)(unsigned short)f2b(o2) << 16);
  *(unsigned*)(ksel + (size_t)((b * 4 + kvh) * 1152 + idx) * 128 + 2 * i) = w;
}

// ---------------- V select + transpose -> v_t[b][kv][128][1152] -----------
__global__ void vsel_kernel(const short* __restrict__ qkv, short* __restrict__ vt) {
  int tid = blockIdx.x * 256 + threadIdx.x;  // B*KV*128*1152 = 1179648
  int idx = tid % 1152;
  int rest = tid / 1152;
  int d = rest & 127;
  int kvh = (rest >> 7) & 3;
  int b = rest >> 9;
  int t = idx < 128 ? idx : idx + 896;
  vt[(size_t)((b * 4 + kvh) * 128 + d) * 1152 + idx] =
      qkv[(size_t)(b * 2048 + t) * 3072 + 2560 + kvh * 128 + d];
}

// ---------------- attention: block=(b,h,qtile64), 4 waves x 16 rows -------
__global__ __launch_bounds__(256) void attn_kernel(const short* __restrict__ qb,
                                                   const short* __restrict__ ksel,
                                                   const short* __restrict__ vt,
                                                   short* __restrict__ ao) {
  __shared__ alignas(16) short Plds[4][16][40];  // per-wave P (16 q-rows x 32 keys, pad 40)
  const int blk = blockIdx.x;
  const int qt = blk & 31, h = (blk >> 5) & 15, b = blk >> 9;
  const int kv = h >> 2;
  const int wave = threadIdx.x >> 6, lane = threadIdx.x & 63;
  const int g = lane >> 4, cl = lane & 15;
  const int q0 = qt * 64 + wave * 16;
  const float scale = 0.08838834764831845f;  // 1/sqrt(128)

  const short* qrow = qb + (size_t)((b * 16 + h) * 2048 + q0 + cl) * 128;
  bf16x8 qf[4];
#pragma unroll
  for (int d = 0; d < 4; ++d) qf[d] = *(const bf16x8*)(qrow + d * 32 + 8 * g);

  f32x4 o[8];
#pragma unroll
  for (int c = 0; c < 8; ++c) o[c] = (f32x4){0.f, 0.f, 0.f, 0.f};
  float m_i[4], l_i[4];
#pragma unroll
  for (int r = 0; r < 4; ++r) { m_i[r] = -1e30f; l_i[r] = 0.f; }

  const short* kbase = ksel + (size_t)(b * 4 + kv) * 1152 * 128;
  const short* vbase = vt + (size_t)(b * 4 + kv) * 128 * 1152;
  int niter = (q0 + 16 + 31) >> 5;  // keys this wave can see, /32 (per-wave bound, no barriers)
  if (niter > 36) niter = 36;

  for (int it = 0; it < niter; ++it) {
    const int kk0 = it * 32;
    f32x4 s0 = (f32x4){0.f, 0.f, 0.f, 0.f}, s1 = (f32x4){0.f, 0.f, 0.f, 0.f};
    const short* kr0 = kbase + (size_t)(kk0 + cl) * 128 + 8 * g;
#pragma unroll
    for (int d = 0; d < 4; ++d) {
      bf16x8 kf0 = *(const bf16x8*)(kr0 + d * 32);
      bf16x8 kf1 = *(const bf16x8*)(kr0 + 16 * 128 + d * 32);
      s0 = __builtin_amdgcn_mfma_f32_16x16x32_bf16(qf[d], kf0, s0, 0, 0, 0);
      s1 = __builtin_amdgcn_mfma_f32_16x16x32_bf16(qf[d], kf1, s1, 0, 0, 0);
    }
#pragma unroll
    for (int r = 0; r < 4; ++r) {
      const int qpos = q0 + 4 * g + r;
      float s0r = s0[r] * scale;
      float s1r = s1[r] * scale;
      const bool v0 = (kk0 + cl) <= qpos;
      const bool v1 = (kk0 + 16 + cl) <= qpos;
      s0r = v0 ? s0r : -1e30f;
      s1r = v1 ? s1r : -1e30f;
      float mx = fmaxf(s0r, s1r);
      mx = fmaxf(mx, __shfl_xor(mx, 1));
      mx = fmaxf(mx, __shfl_xor(mx, 2));
      mx = fmaxf(mx, __shfl_xor(mx, 4));
      mx = fmaxf(mx, __shfl_xor(mx, 8));
      const float mnew = fmaxf(m_i[r], mx);
      const float alpha = __expf(m_i[r] - mnew);
      m_i[r] = mnew;
      float p0 = v0 ? __expf(s0r - mnew) : 0.f;
      float p1 = v1 ? __expf(s1r - mnew) : 0.f;
      float ps = p0 + p1;
      ps += __shfl_xor(ps, 1);
      ps += __shfl_xor(ps, 2);
      ps += __shfl_xor(ps, 4);
      ps += __shfl_xor(ps, 8);
      l_i[r] = l_i[r] * alpha + ps;
#pragma unroll
      for (int c = 0; c < 8; ++c) o[c][r] *= alpha;
      Plds[wave][4 * g + r][cl] = f2b(p0);
      Plds[wave][4 * g + r][16 + cl] = f2b(p1);
    }
    asm volatile("s_waitcnt lgkmcnt(0)" ::: "memory");
    bf16x8 pa = *(const bf16x8*)&Plds[wave][cl][8 * g];
    const short* vrow = vbase + kk0 + 8 * g;
#pragma unroll
    for (int c = 0; c < 8; ++c) {
      bf16x8 vf = *(const bf16x8*)(vrow + (size_t)(c * 16 + cl) * 1152);
      o[c] = __builtin_amdgcn_mfma_f32_16x16x32_bf16(pa, vf, o[c], 0, 0, 0);
    }
  }
#pragma unroll
  for (int r = 0; r < 4; ++r) {
    const float invl = 1.0f / l_i[r];
    short* orow = ao + (size_t)(b * 2048 + q0 + 4 * g + r) * 2048 + h * 128;
#pragma unroll
    for (int c = 0; c < 8; ++c) orow[c * 16 + cl] = f2b(o[c][r] * invl);
  }
}

extern "C" void kernel_launch(void* const* d_in, const int* in_sizes, int n_in,
                              void* d_out, int out_size, void* d_ws, size_t ws_size,
                              hipStream_t stream) {
  const float* x = (const float*)d_in[0];
  const float* Wq = (const float*)d_in[1];
  const float* Wk = (const float*)d_in[2];
  const float* Wv = (const float*)d_in[3];
  const float* Wo = (const float*)d_in[4];
  float* out = (float*)d_out;

  char* ws = (char*)d_ws;
  short* x_bf = (short*)ws;   ws += (size_t)4096 * 2048 * 2;
  short* wqkv_t = (short*)ws; ws += (size_t)3072 * 2048 * 2;
  short* wo_t = (short*)ws;   ws += (size_t)2048 * 2048 * 2;
  short* qkv = (short*)ws;    ws += (size_t)4096 * 3072 * 2;
  short* q_bf = (short*)ws;   ws += (size_t)2 * 16 * 2048 * 128 * 2;
  short* k_sel = (short*)ws;  ws += (size_t)2 * 4 * 1152 * 128 * 2;
  short* v_t = (short*)ws;    ws += (size_t)2 * 4 * 128 * 1152 * 2;
  short* ao = (short*)ws;     ws += (size_t)4096 * 2048 * 2;

  cvt_kernel<<<4096, 256, 0, stream>>>(x, x_bf, 1048576);
  transpose_kernel<<<dim3(64, 64), 256, 0, stream>>>(Wq, wqkv_t, 2048, 2048);
  transpose_kernel<<<dim3(16, 64), 256, 0, stream>>>(Wk, wqkv_t + (size_t)2048 * 2048, 2048, 512);
  transpose_kernel<<<dim3(16, 64), 256, 0, stream>>>(Wv, wqkv_t + (size_t)2560 * 2048, 2048, 512);
  transpose_kernel<<<dim3(64, 64), 256, 0, stream>>>(Wo, wo_t, 2048, 2048);
  gemm_bt<1><<<dim3(24, 32), 256, 0, stream>>>(x_bf, wqkv_t, qkv, 4096, 3072, 2048);
  rope_q_kernel<<<16384, 256, 0, stream>>>(qkv, q_bf);
  rope_k_kernel<<<4096, 256, 0, stream>>>(qkv, k_sel);
  vsel_kernel<<<4608, 256, 0, stream>>>(qkv, v_t);
  attn_kernel<<<1024, 256, 0, stream>>>(q_bf, k_sel, v_t, ao);
  gemm_bt<0><<<dim3(16, 32), 256, 0, stream>>>(ao, wo_t, out, 4096, 2048, 2048);
}

// Round 2
// 333.221 us; speedup vs baseline: 1.6685x; 1.6685x over previous
//
#include <hip/hip_runtime.h>
#include <hip/hip_bf16.h>
#include <math.h>

typedef __attribute__((ext_vector_type(4))) float f32x4;
typedef __attribute__((ext_vector_type(8))) short bf16x8;

#define LDSP(p)  ((__attribute__((address_space(3))) void*)(p))
#define GMEMP(p) ((const __attribute__((address_space(1))) void*)(p))

__device__ __forceinline__ short f2b(float f) {
  __hip_bfloat16 h = __float2bfloat16(f);
  return __builtin_bit_cast(short, h);
}
__device__ __forceinline__ float b2f(short s) {
  __hip_bfloat16 h = __builtin_bit_cast(__hip_bfloat16, s);
  return __bfloat162float(h);
}
__device__ __forceinline__ unsigned pack2(float a, float b) {
  return (unsigned)(unsigned short)f2b(a) | ((unsigned)(unsigned short)f2b(b) << 16);
}

// ---------------- elementwise f32 -> bf16 (8 elems/thread) ----------------
__global__ void cvt_kernel(const float* __restrict__ src, short* __restrict__ dst, int n8) {
  int i = blockIdx.x * blockDim.x + threadIdx.x;
  if (i >= n8) return;
  const float4* s4 = (const float4*)src;
  float4 a = s4[2 * i], b = s4[2 * i + 1];
  bf16x8 o;
  o[0] = f2b(a.x); o[1] = f2b(a.y); o[2] = f2b(a.z); o[3] = f2b(a.w);
  o[4] = f2b(b.x); o[5] = f2b(b.y); o[6] = f2b(b.z); o[7] = f2b(b.w);
  *(bf16x8*)(dst + (size_t)i * 8) = o;
}

// ---------------- f32 [rows][cols] -> bf16 [cols][rows] -------------------
__global__ void transpose_kernel(const float* __restrict__ src, short* __restrict__ dst,
                                 int rows, int cols) {
  __shared__ float tile[32][33];
  int c0 = blockIdx.x * 32, r0 = blockIdx.y * 32;
  int tx = threadIdx.x & 31, ty = threadIdx.x >> 5;  // 256 thr = 32 x 8
  for (int i = ty; i < 32; i += 8)
    tile[i][tx] = src[(size_t)(r0 + i) * cols + c0 + tx];
  __syncthreads();
  for (int i = ty; i < 32; i += 8)
    dst[(size_t)(c0 + i) * rows + r0 + tx] = f2b(tile[tx][i]);
}

// ---------------- bf16 GEMM: C = A[M][K] @ B[K][N], Bt = B^T [N][K] -------
template <int OUTBF>
__global__ __launch_bounds__(256) void gemm_bt(const short* __restrict__ A,
                                               const short* __restrict__ Bt,
                                               void* __restrict__ Cv,
                                               int M, int N, int K) {
  __shared__ alignas(16) short As[128 * 32];
  __shared__ alignas(16) short Bs[128 * 32];
  const int m0 = blockIdx.y * 128, n0 = blockIdx.x * 128;
  const int wave = threadIdx.x >> 6, lane = threadIdx.x & 63;
  const int g = lane >> 4, cl = lane & 15;
  const int wr = (wave >> 1) * 64, wc = (wave & 1) * 64;
  f32x4 acc[4][4];
#pragma unroll
  for (int i = 0; i < 4; ++i)
#pragma unroll
    for (int j = 0; j < 4; ++j) acc[i][j] = (f32x4){0.f, 0.f, 0.f, 0.f};

  const size_t lda = (size_t)K;
  for (int kt = 0; kt < K; kt += 32) {
#pragma unroll
    for (int c = 0; c < 2; ++c) {
      int e = (wave * 2 + c) * 512;          // uniform per wave (shorts)
      int el = e + lane * 8;                 // this lane's element
      const short* ga = A + (size_t)(m0 + (el >> 5)) * lda + kt + (el & 31);
      __builtin_amdgcn_global_load_lds(GMEMP(ga), LDSP(&As[e]), 16, 0, 0);
      const short* gb = Bt + (size_t)(n0 + (el >> 5)) * lda + kt + (el & 31);
      __builtin_amdgcn_global_load_lds(GMEMP(gb), LDSP(&Bs[e]), 16, 0, 0);
    }
    __syncthreads();
    bf16x8 af[4], bfr[4];
#pragma unroll
    for (int i = 0; i < 4; ++i)
      af[i] = *(const bf16x8*)&As[(wr + 16 * i + cl) * 32 + 8 * g];
#pragma unroll
    for (int j = 0; j < 4; ++j)
      bfr[j] = *(const bf16x8*)&Bs[(wc + 16 * j + cl) * 32 + 8 * g];
#pragma unroll
    for (int i = 0; i < 4; ++i)
#pragma unroll
      for (int j = 0; j < 4; ++j)
        acc[i][j] = __builtin_amdgcn_mfma_f32_16x16x32_bf16(af[i], bfr[j], acc[i][j], 0, 0, 0);
    __syncthreads();
  }
#pragma unroll
  for (int i = 0; i < 4; ++i)
#pragma unroll
    for (int j = 0; j < 4; ++j)
#pragma unroll
      for (int r = 0; r < 4; ++r) {
        int row = m0 + wr + 16 * i + 4 * g + r;
        int col = n0 + wc + 16 * j + cl;
        if (OUTBF)
          ((short*)Cv)[(size_t)row * N + col] = f2b(acc[i][j][r]);
        else
          ((float*)Cv)[(size_t)row * N + col] = acc[i][j][r];
      }
}

// ---------------- RoPE on q: qkv[row][h*128+2i..] -> q_bf[b][h][t][..] ----
__global__ void rope_q_kernel(const short* __restrict__ qkv, short* __restrict__ qb) {
  int tid = blockIdx.x * 256 + threadIdx.x;  // B*T*H*64 = 4194304
  int i = tid & 63;
  int h = (tid >> 6) & 15;
  int row = tid >> 10;  // b*2048 + t
  int t = row & 2047;
  int b = row >> 11;
  unsigned u = *(const unsigned*)(qkv + (size_t)row * 3072 + h * 128 + 2 * i);
  float x1 = b2f((short)(u & 0xffff));
  float x2 = b2f((short)(u >> 16));
  float inv = exp2f(-0.20762050593046f * (float)i);  // 10000^(-i/64)
  float ang = (float)t * inv;
  float sn, cs;
  __sincosf(ang, &sn, &cs);
  float o1 = x1 * cs - x2 * sn;
  float o2 = x1 * sn + x2 * cs;
  unsigned w = pack2(o1, o2);
  *(unsigned*)(qb + (size_t)((b * 16 + h) * 2048 + t) * 128 + 2 * i) = w;
}

// ---------------- RoPE on k + window select -> k_sel[b][kv][1152][128] ----
__global__ void rope_k_kernel(const short* __restrict__ qkv, short* __restrict__ ksel) {
  int tid = blockIdx.x * 256 + threadIdx.x;  // B*T*KV*64 = 1048576
  int i = tid & 63;
  int kvh = (tid >> 6) & 3;
  int row = tid >> 8;
  int t = row & 2047;
  int b = row >> 11;
  int idx = t < 128 ? t : (t >= 1024 ? t - 896 : -1);
  if (idx < 0) return;
  unsigned u = *(const unsigned*)(qkv + (size_t)row * 3072 + 2048 + kvh * 128 + 2 * i);
  float x1 = b2f((short)(u & 0xffff));
  float x2 = b2f((short)(u >> 16));
  float inv = exp2f(-0.20762050593046f * (float)i);
  float ang = (float)t * inv;
  float sn, cs;
  __sincosf(ang, &sn, &cs);
  float o1 = x1 * cs - x2 * sn;
  float o2 = x1 * sn + x2 * cs;
  unsigned w = pack2(o1, o2);
  *(unsigned*)(ksel + (size_t)((b * 4 + kvh) * 1152 + idx) * 128 + 2 * i) = w;
}

// ---------------- V select + transpose -> v_t[b][kv][128][1152] -----------
__global__ void vsel_kernel(const short* __restrict__ qkv, short* __restrict__ vt) {
  int tid = blockIdx.x * 256 + threadIdx.x;  // B*KV*128*1152 = 1179648
  int idx = tid % 1152;
  int rest = tid / 1152;
  int d = rest & 127;
  int kvh = (rest >> 7) & 3;
  int b = rest >> 9;
  int t = idx < 128 ? idx : idx + 896;
  vt[(size_t)((b * 4 + kvh) * 128 + d) * 1152 + idx] =
      qkv[(size_t)(b * 2048 + t) * 3072 + 2560 + kvh * 128 + d];
}

// ---------------- attention v2 ------------------------------------------
// block = (b,h,qtile of 64 rows), 4 waves x 16 q-rows. 64-key chunks.
// Swapped-operand MFMA: each lane owns ONE q-row (q = q0w + (lane&15)).
// K double-buffered LDS (prefetch, counted vmcnt), V single-buffered,
// both XOR-swizzled (col ^= (row&7)<<3) with pre-swizzled global source.
__global__ __launch_bounds__(256) void attn_kernel(const short* __restrict__ qb,
                                                   const short* __restrict__ ksel,
                                                   const short* __restrict__ vt,
                                                   short* __restrict__ ao) {
  __shared__ alignas(16) short Ksm[2][8192];   // [64 keys][128 d] bf16, swizzled
  __shared__ alignas(16) short Vsm[8192];      // [128 d][64 keys] bf16, swizzled
  __shared__ alignas(16) short Psm[4][16][72]; // per-wave P [16 q][64 keys +pad]

  const int blk = blockIdx.x;
  const int qt = 31 - (blk >> 5);              // heavy tiles first
  const int h = blk & 15, b = (blk >> 4) & 1;
  const int kv = h >> 2;
  const int wave = threadIdx.x >> 6, lane = threadIdx.x & 63;
  const int g = lane >> 4, cl = lane & 15;
  const int q0w = qt * 64 + wave * 16;
  const int qi = q0w + cl;                     // this lane's q-row
  const float scale = 0.08838834764831845f;    // 1/sqrt(128)
  const int niter = (qt + 1 < 18) ? (qt + 1) : 18;

  const short* kselb = ksel + (size_t)(b * 4 + kv) * 1152 * 128;
  const short* vtb = vt + (size_t)(b * 4 + kv) * 128 * 1152;

  // Q fragments for this lane's q-row (B-operand of swapped QK^T)
  const short* qrow = qb + (size_t)((b * 16 + h) * 2048 + qi) * 128;
  bf16x8 qf[4];
#pragma unroll
  for (int d = 0; d < 4; ++d) qf[d] = *(const bf16x8*)(qrow + d * 32 + 8 * g);

  f32x4 o[8];
#pragma unroll
  for (int c = 0; c < 8; ++c) o[c] = (f32x4){0.f, 0.f, 0.f, 0.f};
  float m_i = -1e30f, l_i = 0.f;

  // ---- prologue: stage K chunk 0 into buf 0 ----
#pragma unroll
  for (int i = 0; i < 4; ++i) {
    int base = i * 2048 + wave * 512;
    int Lel = base + lane * 8;
    int kr = Lel >> 7;
    int kc = (Lel & 127) ^ ((kr & 7) << 3);
    __builtin_amdgcn_global_load_lds(GMEMP(kselb + (size_t)kr * 128 + kc),
                                     LDSP(&Ksm[0][base]), 16, 0, 0);
  }
  asm volatile("s_waitcnt vmcnt(0)" ::: "memory");
  __builtin_amdgcn_s_barrier();
  asm volatile("" ::: "memory");

  int cur = 0;
  for (int t = 0; t < niter; ++t) {
    const int kk0 = t * 64;
    // ---- stage V(t) (oldest vm ops), then prefetch K(t+1) ----
#pragma unroll
    for (int i = 0; i < 4; ++i) {
      int base = i * 2048 + wave * 512;
      int Lel = base + lane * 8;
      int vr = Lel >> 6;
      int vc = (Lel & 63) ^ ((vr & 7) << 3);
      __builtin_amdgcn_global_load_lds(GMEMP(vtb + (size_t)vr * 1152 + kk0 + vc),
                                       LDSP(&Vsm[base]), 16, 0, 0);
    }
    const bool lastk = (t + 1 >= niter);
    if (!lastk) {
#pragma unroll
      for (int i = 0; i < 4; ++i) {
        int base = i * 2048 + wave * 512;
        int Lel = base + lane * 8;
        int kr = Lel >> 7;
        int kc = (Lel & 127) ^ ((kr & 7) << 3);
        __builtin_amdgcn_global_load_lds(GMEMP(kselb + (size_t)(kk0 + 64 + kr) * 128 + kc),
                                         LDSP(&Ksm[cur ^ 1][base]), 16, 0, 0);
      }
    }

    // ---- QK^T (swapped): S^T[key][q], lane owns q=qi, 16 keys in regs ----
    f32x4 s[4];
#pragma unroll
    for (int j = 0; j < 4; ++j) s[j] = (f32x4){0.f, 0.f, 0.f, 0.f};
    const short* kb = &Ksm[cur][0];
    const int sw = (cl & 7) << 3;
#pragma unroll
    for (int j = 0; j < 4; ++j) {
      const int rs = (16 * j + cl) * 128;
#pragma unroll
      for (int d = 0; d < 4; ++d) {
        bf16x8 kf = *(const bf16x8*)&kb[rs + ((d * 32 + 8 * g) ^ sw)];
        s[j] = __builtin_amdgcn_mfma_f32_16x16x32_bf16(kf, qf[d], s[j], 0, 0, 0);
      }
    }

    // ---- online softmax: all values for lane's own q-row ----
    float sv[4][4];
    float mx = -1e30f;
#pragma unroll
    for (int j = 0; j < 4; ++j)
#pragma unroll
      for (int r = 0; r < 4; ++r) {
        int key = kk0 + 16 * j + 4 * g + r;
        float v = s[j][r] * scale;
        v = (key <= qi) ? v : -1e30f;
        sv[j][r] = v;
        mx = fmaxf(mx, v);
      }
    mx = fmaxf(mx, __shfl_xor(mx, 16));
    mx = fmaxf(mx, __shfl_xor(mx, 32));
    const float mnew = fmaxf(m_i, mx);
    const float alpha = __expf(m_i - mnew);
    m_i = mnew;
    float ls = 0.f;
#pragma unroll
    for (int j = 0; j < 4; ++j) {
      float p0 = __expf(sv[j][0] - mnew);
      float p1 = __expf(sv[j][1] - mnew);
      float p2 = __expf(sv[j][2] - mnew);
      float p3 = __expf(sv[j][3] - mnew);
      ls += (p0 + p1) + (p2 + p3);
      uint2 w;
      w.x = pack2(p0, p1);
      w.y = pack2(p2, p3);
      *(uint2*)&Psm[wave][cl][16 * j + 4 * g] = w;
    }
    ls += __shfl_xor(ls, 16);
    ls += __shfl_xor(ls, 32);
    l_i = l_i * alpha + ls;
#pragma unroll
    for (int c = 0; c < 8; ++c)
#pragma unroll
      for (int r = 0; r < 4; ++r) o[c][r] *= alpha;

    // ---- barrier A: V(t) staged by all waves is ready; K(t+1) stays in flight
    if (!lastk)
      asm volatile("s_waitcnt vmcnt(4)" ::: "memory");
    else
      asm volatile("s_waitcnt vmcnt(0)" ::: "memory");
    __builtin_amdgcn_s_barrier();
    asm volatile("" ::: "memory");

    // ---- PV (swapped): O^T[d][q] += V^T[d][key] @ P^T[key][q] ----
    asm volatile("s_waitcnt lgkmcnt(0)" ::: "memory");
    bf16x8 pb0 = *(const bf16x8*)&Psm[wave][cl][8 * g];
    bf16x8 pb1 = *(const bf16x8*)&Psm[wave][cl][32 + 8 * g];
#pragma unroll
    for (int c = 0; c < 8; ++c) {
      const int rowd = c * 16 + cl;
      const int rvs = rowd * 64;
      bf16x8 v0 = *(const bf16x8*)&Vsm[rvs + ((8 * g) ^ sw)];
      bf16x8 v1 = *(const bf16x8*)&Vsm[rvs + ((32 + 8 * g) ^ sw)];
      o[c] = __builtin_amdgcn_mfma_f32_16x16x32_bf16(v0, pb0, o[c], 0, 0, 0);
      o[c] = __builtin_amdgcn_mfma_f32_16x16x32_bf16(v1, pb1, o[c], 0, 0, 0);
    }

    // ---- barrier B: K(t+1) landed; Vsm free for next stage ----
    asm volatile("s_waitcnt vmcnt(0)" ::: "memory");
    __builtin_amdgcn_s_barrier();
    asm volatile("" ::: "memory");
    cur ^= 1;
  }

  // ---- epilogue: transpose O^T -> O via per-wave LDS (reuse Ksm) ----
  short* Ol = &Ksm[0][0] + wave * 2176;  // 16 q-rows x 136 (128 d + pad)
  const float invl = 1.0f / l_i;
#pragma unroll
  for (int c = 0; c < 8; ++c) {
    uint2 w;
    w.x = pack2(o[c][0] * invl, o[c][1] * invl);
    w.y = pack2(o[c][2] * invl, o[c][3] * invl);
    *(uint2*)&Ol[cl * 136 + c * 16 + 4 * g] = w;
  }
  asm volatile("s_waitcnt lgkmcnt(0)" ::: "memory");
  const int rowq = lane & 15, seg = lane >> 4;
  const short* srcl = Ol + rowq * 136 + seg * 32;
  short* dst = ao + (size_t)(b * 2048 + q0w + rowq) * 2048 + h * 128 + seg * 32;
#pragma unroll
  for (int k = 0; k < 4; ++k)
    *(bf16x8*)(dst + 8 * k) = *(const bf16x8*)(srcl + 8 * k);
}

extern "C" void kernel_launch(void* const* d_in, const int* in_sizes, int n_in,
                              void* d_out, int out_size, void* d_ws, size_t ws_size,
                              hipStream_t stream) {
  const float* x = (const float*)d_in[0];
  const float* Wq = (const float*)d_in[1];
  const float* Wk = (const float*)d_in[2];
  const float* Wv = (const float*)d_in[3];
  const float* Wo = (const float*)d_in[4];
  float* out = (float*)d_out;

  char* ws = (char*)d_ws;
  short* x_bf = (short*)ws;   ws += (size_t)4096 * 2048 * 2;
  short* wqkv_t = (short*)ws; ws += (size_t)3072 * 2048 * 2;
  short* wo_t = (short*)ws;   ws += (size_t)2048 * 2048 * 2;
  short* qkv = (short*)ws;    ws += (size_t)4096 * 3072 * 2;
  short* q_bf = (short*)ws;   ws += (size_t)2 * 16 * 2048 * 128 * 2;
  short* k_sel = (short*)ws;  ws += (size_t)2 * 4 * 1152 * 128 * 2;
  short* v_t = (short*)ws;    ws += (size_t)2 * 4 * 128 * 1152 * 2;
  short* ao = (short*)ws;     ws += (size_t)4096 * 2048 * 2;

  cvt_kernel<<<4096, 256, 0, stream>>>(x, x_bf, 1048576);
  transpose_kernel<<<dim3(64, 64), 256, 0, stream>>>(Wq, wqkv_t, 2048, 2048);
  transpose_kernel<<<dim3(16, 64), 256, 0, stream>>>(Wk, wqkv_t + (size_t)2048 * 2048, 2048, 512);
  transpose_kernel<<<dim3(16, 64), 256, 0, stream>>>(Wv, wqkv_t + (size_t)2560 * 2048, 2048, 512);
  transpose_kernel<<<dim3(64, 64), 256, 0, stream>>>(Wo, wo_t, 2048, 2048);
  gemm_bt<1><<<dim3(24, 32), 256, 0, stream>>>(x_bf, wqkv_t, qkv, 4096, 3072, 2048);
  rope_q_kernel<<<16384, 256, 0, stream>>>(qkv, q_bf);
  rope_k_kernel<<<4096, 256, 0, stream>>>(qkv, k_sel);
  vsel_kernel<<<4608, 256, 0, stream>>>(qkv, v_t);
  attn_kernel<<<1024, 256, 0, stream>>>(q_bf, k_sel, v_t, ao);
  gemm_bt<0><<<dim3(16, 32), 256, 0, stream>>>(ao, wo_t, out, 4096, 2048, 2048);
}

// Round 3
// 321.025 us; speedup vs baseline: 1.7319x; 1.0380x over previous
//
#include <hip/hip_runtime.h>
#include <hip/hip_bf16.h>
#include <math.h>

typedef __attribute__((ext_vector_type(4))) float f32x4;
typedef __attribute__((ext_vector_type(8))) short bf16x8;

#define LDSP(p)  ((__attribute__((address_space(3))) void*)(p))
#define GMEMP(p) ((const __attribute__((address_space(1))) void*)(p))

__device__ __forceinline__ short f2b(float f) {
  __hip_bfloat16 h = __float2bfloat16(f);
  return __builtin_bit_cast(short, h);
}
__device__ __forceinline__ float b2f(short s) {
  __hip_bfloat16 h = __builtin_bit_cast(__hip_bfloat16, s);
  return __bfloat162float(h);
}
__device__ __forceinline__ unsigned pack2(float a, float b) {
  return (unsigned)(unsigned short)f2b(a) | ((unsigned)(unsigned short)f2b(b) << 16);
}

// ---------------- elementwise f32 -> bf16 (8 elems/thread) ----------------
__global__ void cvt_kernel(const float* __restrict__ src, short* __restrict__ dst, int n8) {
  int i = blockIdx.x * blockDim.x + threadIdx.x;
  if (i >= n8) return;
  const float4* s4 = (const float4*)src;
  float4 a = s4[2 * i], b = s4[2 * i + 1];
  bf16x8 o;
  o[0] = f2b(a.x); o[1] = f2b(a.y); o[2] = f2b(a.z); o[3] = f2b(a.w);
  o[4] = f2b(b.x); o[5] = f2b(b.y); o[6] = f2b(b.z); o[7] = f2b(b.w);
  *(bf16x8*)(dst + (size_t)i * 8) = o;
}

// ---------------- all 4 weight transposes in one kernel -------------------
// gx: 0-63 Wq, 64-79 Wk, 80-95 Wv, 96-159 Wo. rows=2048 for all.
__global__ void transpose_all(const float* __restrict__ Wq, const float* __restrict__ Wk,
                              const float* __restrict__ Wv, const float* __restrict__ Wo,
                              short* __restrict__ wqkv_t, short* __restrict__ wo_t) {
  __shared__ float tile[32][33];
  int gx = blockIdx.x;
  const float* src; short* dst; int cols, cx;
  if (gx < 64)       { src = Wq; dst = wqkv_t;                        cols = 2048; cx = gx; }
  else if (gx < 80)  { src = Wk; dst = wqkv_t + (size_t)2048 * 2048;  cols = 512;  cx = gx - 64; }
  else if (gx < 96)  { src = Wv; dst = wqkv_t + (size_t)2560 * 2048;  cols = 512;  cx = gx - 80; }
  else               { src = Wo; dst = wo_t;                          cols = 2048; cx = gx - 96; }
  int c0 = cx * 32, r0 = blockIdx.y * 32;
  int tx = threadIdx.x & 31, ty = threadIdx.x >> 5;
  for (int i = ty; i < 32; i += 8)
    tile[i][tx] = src[(size_t)(r0 + i) * cols + c0 + tx];
  __syncthreads();
  for (int i = ty; i < 32; i += 8)
    dst[(size_t)(c0 + i) * 2048 + r0 + tx] = f2b(tile[tx][i]);
}

// ---------------- bf16 GEMM: C = A[M][K] @ B[K][N], Bt = B^T [N][K] -------
// 128x128 tile, BK=32, 4 waves. Ring-3 LDS, counted vmcnt(4), raw barrier,
// XOR swizzle col^=((row>>1)&3)<<3 (pre-swizzled source + swizzled read).
template <int OUTBF>
__global__ __launch_bounds__(256) void gemm_bt(const short* __restrict__ A,
                                               const short* __restrict__ Bt,
                                               void* __restrict__ Cv,
                                               int M, int N, int K) {
  __shared__ alignas(16) short As[3][128 * 32];
  __shared__ alignas(16) short Bs[3][128 * 32];
  const int m0 = blockIdx.y * 128, n0 = blockIdx.x * 128;
  const int wave = threadIdx.x >> 6, lane = threadIdx.x & 63;
  const int g = lane >> 4, cl = lane & 15;
  const int wr = (wave >> 1) * 64, wc = (wave & 1) * 64;
  const int tid = threadIdx.x;
  f32x4 acc[4][4];
#pragma unroll
  for (int i = 0; i < 4; ++i)
#pragma unroll
    for (int j = 0; j < 4; ++j) acc[i][j] = (f32x4){0.f, 0.f, 0.f, 0.f};

  // staging: LDS element e (of 4096) holds A[m0 + (e>>5)][kt + 8*(j ^ ((r>>1)&3)) + (e&7)]
  const int e0 = tid * 8;
#define STAGE(kt, s)                                                                        \
  {                                                                                         \
    _Pragma("unroll") for (int c = 0; c < 2; ++c) {                                         \
      int e = c * 2048 + e0;                                                                \
      int r = e >> 5;                                                                       \
      int j = (e >> 3) & 3;                                                                 \
      int col = (kt) + 8 * (j ^ ((r >> 1) & 3));                                            \
      __builtin_amdgcn_global_load_lds(GMEMP(A + (size_t)(m0 + r) * K + col),               \
                                       LDSP(&As[s][e]), 16, 0, 0);                          \
      __builtin_amdgcn_global_load_lds(GMEMP(Bt + (size_t)(n0 + r) * K + col),              \
                                       LDSP(&Bs[s][e]), 16, 0, 0);                          \
    }                                                                                       \
  }

  const int nkt = K >> 5;
  STAGE(0, 0);
  STAGE(32, 1);
  asm volatile("s_waitcnt vmcnt(4)" ::: "memory");
  __builtin_amdgcn_s_barrier();
  asm volatile("" ::: "memory");

  int s = 0;
  for (int t = 0; t < nkt; ++t) {
    if (t + 2 < nkt) {
      int s2 = s + 2; if (s2 >= 3) s2 -= 3;
      STAGE((t + 2) << 5, s2);
    }
    bf16x8 af[4], bfr[4];
#pragma unroll
    for (int i = 0; i < 4; ++i) {
      int R = wr + 16 * i + cl;
      af[i] = *(const bf16x8*)&As[s][R * 32 + 8 * (g ^ ((R >> 1) & 3))];
    }
#pragma unroll
    for (int j = 0; j < 4; ++j) {
      int R = wc + 16 * j + cl;
      bfr[j] = *(const bf16x8*)&Bs[s][R * 32 + 8 * (g ^ ((R >> 1) & 3))];
    }
    __builtin_amdgcn_s_setprio(1);
#pragma unroll
    for (int i = 0; i < 4; ++i)
#pragma unroll
      for (int j = 0; j < 4; ++j)
        acc[i][j] = __builtin_amdgcn_mfma_f32_16x16x32_bf16(af[i], bfr[j], acc[i][j], 0, 0, 0);
    __builtin_amdgcn_s_setprio(0);
    asm volatile("s_waitcnt vmcnt(4)" ::: "memory");
    __builtin_amdgcn_s_barrier();
    asm volatile("" ::: "memory");
    if (++s >= 3) s -= 3;
  }
#undef STAGE
#pragma unroll
  for (int i = 0; i < 4; ++i)
#pragma unroll
    for (int j = 0; j < 4; ++j)
#pragma unroll
      for (int r = 0; r < 4; ++r) {
        int row = m0 + wr + 16 * i + 4 * g + r;
        int col = n0 + wc + 16 * j + cl;
        if (OUTBF)
          ((short*)Cv)[(size_t)row * N + col] = f2b(acc[i][j][r]);
        else
          ((float*)Cv)[(size_t)row * N + col] = acc[i][j][r];
      }
}

// ---------------- fused postprocess: rope_q | rope_k | vsel ---------------
__global__ void pp_kernel(const short* __restrict__ qkv, short* __restrict__ qb,
                          short* __restrict__ ksel, short* __restrict__ vt) {
  int blk = blockIdx.x;
  if (blk < 16384) {
    // rope_q
    int tid = blk * 256 + threadIdx.x;
    int i = tid & 63;
    int h = (tid >> 6) & 15;
    int row = tid >> 10;
    int t = row & 2047;
    int b = row >> 11;
    unsigned u = *(const unsigned*)(qkv + (size_t)row * 3072 + h * 128 + 2 * i);
    float x1 = b2f((short)(u & 0xffff));
    float x2 = b2f((short)(u >> 16));
    float inv = exp2f(-0.20762050593046f * (float)i);
    float ang = (float)t * inv;
    float sn, cs;
    __sincosf(ang, &sn, &cs);
    unsigned w = pack2(x1 * cs - x2 * sn, x1 * sn + x2 * cs);
    *(unsigned*)(qb + (size_t)((b * 16 + h) * 2048 + t) * 128 + 2 * i) = w;
  } else if (blk < 16384 + 4096) {
    // rope_k + window select
    int tid = (blk - 16384) * 256 + threadIdx.x;
    int i = tid & 63;
    int kvh = (tid >> 6) & 3;
    int row = tid >> 8;
    int t = row & 2047;
    int b = row >> 11;
    int idx = t < 128 ? t : (t >= 1024 ? t - 896 : -1);
    if (idx < 0) return;
    unsigned u = *(const unsigned*)(qkv + (size_t)row * 3072 + 2048 + kvh * 128 + 2 * i);
    float x1 = b2f((short)(u & 0xffff));
    float x2 = b2f((short)(u >> 16));
    float inv = exp2f(-0.20762050593046f * (float)i);
    float ang = (float)t * inv;
    float sn, cs;
    __sincosf(ang, &sn, &cs);
    unsigned w = pack2(x1 * cs - x2 * sn, x1 * sn + x2 * cs);
    *(unsigned*)(ksel + (size_t)((b * 4 + kvh) * 1152 + idx) * 128 + 2 * i) = w;
  } else {
    // V select + transpose
    int tid = (blk - 20480) * 256 + threadIdx.x;
    int idx = tid % 1152;
    int rest = tid / 1152;
    int d = rest & 127;
    int kvh = (rest >> 7) & 3;
    int b = rest >> 9;
    int t = idx < 128 ? idx : idx + 896;
    vt[(size_t)((b * 4 + kvh) * 128 + d) * 1152 + idx] =
        qkv[(size_t)(b * 2048 + t) * 3072 + 2560 + kvh * 128 + d];
  }
}

// ---------------- attention v3 ------------------------------------------
// block = (b,h,qtile of 64 rows), 4 waves x 16 q-rows. 64-key chunks.
// Swapped-operand MFMA; K AND V double-buffered, prefetched at iter top
// (issue-early/consume-next-iter); one barrier per iteration; setprio.
__global__ __launch_bounds__(256) void attn_kernel(const short* __restrict__ qb,
                                                   const short* __restrict__ ksel,
                                                   const short* __restrict__ vt,
                                                   short* __restrict__ ao) {
  __shared__ alignas(16) short Ksm[2][8192];   // [64 keys][128 d], swizzled
  __shared__ alignas(16) short Vsm[2][8192];   // [128 d][64 keys], swizzled
  __shared__ alignas(16) short Psm[4][16][72]; // per-wave P [16 q][64 keys +pad]

  const int blk = blockIdx.x;
  const int qt = 31 - (blk >> 5);              // heavy tiles first
  const int h = blk & 15, b = (blk >> 4) & 1;
  const int kv = h >> 2;
  const int wave = threadIdx.x >> 6, lane = threadIdx.x & 63;
  const int g = lane >> 4, cl = lane & 15;
  const int q0w = qt * 64 + wave * 16;
  const int qi = q0w + cl;
  const float scale = 0.08838834764831845f;
  const int niter = (qt + 1 < 18) ? (qt + 1) : 18;

  const short* kselb = ksel + (size_t)(b * 4 + kv) * 1152 * 128;
  const short* vtb = vt + (size_t)(b * 4 + kv) * 128 * 1152;

  const short* qrow = qb + (size_t)((b * 16 + h) * 2048 + qi) * 128;
  bf16x8 qf[4];
#pragma unroll
  for (int d = 0; d < 4; ++d) qf[d] = *(const bf16x8*)(qrow + d * 32 + 8 * g);

  f32x4 o[8];
#pragma unroll
  for (int c = 0; c < 8; ++c) o[c] = (f32x4){0.f, 0.f, 0.f, 0.f};
  float m_i = -1e30f, l_i = 0.f;

#define STAGEK(kk0, buf)                                                                  \
  {                                                                                       \
    _Pragma("unroll") for (int i = 0; i < 4; ++i) {                                       \
      int base = i * 2048 + wave * 512;                                                   \
      int Lel = base + lane * 8;                                                          \
      int kr = Lel >> 7;                                                                  \
      int kc = (Lel & 127) ^ ((kr & 7) << 3);                                             \
      __builtin_amdgcn_global_load_lds(GMEMP(kselb + (size_t)((kk0) + kr) * 128 + kc),    \
                                       LDSP(&Ksm[buf][base]), 16, 0, 0);                  \
    }                                                                                     \
  }
#define STAGEV(kk0, buf)                                                                  \
  {                                                                                       \
    _Pragma("unroll") for (int i = 0; i < 4; ++i) {                                       \
      int base = i * 2048 + wave * 512;                                                   \
      int Lel = base + lane * 8;                                                          \
      int vr = Lel >> 6;                                                                  \
      int vc = (Lel & 63) ^ ((vr & 7) << 3);                                              \
      __builtin_amdgcn_global_load_lds(GMEMP(vtb + (size_t)vr * 1152 + (kk0) + vc),       \
                                       LDSP(&Vsm[buf][base]), 16, 0, 0);                  \
    }                                                                                     \
  }

  STAGEK(0, 0);
  STAGEV(0, 0);
  asm volatile("s_waitcnt vmcnt(0)" ::: "memory");
  __builtin_amdgcn_s_barrier();
  asm volatile("" ::: "memory");

  for (int t = 0; t < niter; ++t) {
    const int cur = t & 1;
    const int kk0 = t * 64;
    if (t + 1 < niter) {
      STAGEK(kk0 + 64, cur ^ 1);
      STAGEV(kk0 + 64, cur ^ 1);
    }

    // ---- QK^T (swapped): lane owns q=qi, 16 keys/frag in regs ----
    f32x4 sf[4];
#pragma unroll
    for (int j = 0; j < 4; ++j) sf[j] = (f32x4){0.f, 0.f, 0.f, 0.f};
    const short* kb = &Ksm[cur][0];
    const int sw = (cl & 7) << 3;
    __builtin_amdgcn_s_setprio(1);
#pragma unroll
    for (int j = 0; j < 4; ++j) {
      const int rs = (16 * j + cl) * 128;
#pragma unroll
      for (int d = 0; d < 4; ++d) {
        bf16x8 kf = *(const bf16x8*)&kb[rs + ((d * 32 + 8 * g) ^ sw)];
        sf[j] = __builtin_amdgcn_mfma_f32_16x16x32_bf16(kf, qf[d], sf[j], 0, 0, 0);
      }
    }
    __builtin_amdgcn_s_setprio(0);

    // ---- online softmax (lane-local row) ----
    float sv[4][4];
    float mx = -1e30f;
#pragma unroll
    for (int j = 0; j < 4; ++j)
#pragma unroll
      for (int r = 0; r < 4; ++r) {
        int key = kk0 + 16 * j + 4 * g + r;
        float v = sf[j][r] * scale;
        v = (key <= qi) ? v : -1e30f;
        sv[j][r] = v;
        mx = fmaxf(mx, v);
      }
    mx = fmaxf(mx, __shfl_xor(mx, 16));
    mx = fmaxf(mx, __shfl_xor(mx, 32));
    const float mnew = fmaxf(m_i, mx);
    const float alpha = __expf(m_i - mnew);
    m_i = mnew;
    float ls = 0.f;
#pragma unroll
    for (int j = 0; j < 4; ++j) {
      float p0 = __expf(sv[j][0] - mnew);
      float p1 = __expf(sv[j][1] - mnew);
      float p2 = __expf(sv[j][2] - mnew);
      float p3 = __expf(sv[j][3] - mnew);
      ls += (p0 + p1) + (p2 + p3);
      uint2 w;
      w.x = pack2(p0, p1);
      w.y = pack2(p2, p3);
      *(uint2*)&Psm[wave][cl][16 * j + 4 * g] = w;
    }
    ls += __shfl_xor(ls, 16);
    ls += __shfl_xor(ls, 32);
    l_i = l_i * alpha + ls;
#pragma unroll
    for (int c = 0; c < 8; ++c)
#pragma unroll
      for (int r = 0; r < 4; ++r) o[c][r] *= alpha;

    // ---- PV (swapped): V(t) was staged last iteration (or prologue) ----
    asm volatile("s_waitcnt lgkmcnt(0)" ::: "memory");
    bf16x8 pb0 = *(const bf16x8*)&Psm[wave][cl][8 * g];
    bf16x8 pb1 = *(const bf16x8*)&Psm[wave][cl][32 + 8 * g];
    const short* vb = &Vsm[cur][0];
    __builtin_amdgcn_s_setprio(1);
#pragma unroll
    for (int c = 0; c < 8; ++c) {
      const int rvs = (c * 16 + cl) * 64;
      bf16x8 v0 = *(const bf16x8*)&vb[rvs + ((8 * g) ^ sw)];
      bf16x8 v1 = *(const bf16x8*)&vb[rvs + ((32 + 8 * g) ^ sw)];
      o[c] = __builtin_amdgcn_mfma_f32_16x16x32_bf16(v0, pb0, o[c], 0, 0, 0);
      o[c] = __builtin_amdgcn_mfma_f32_16x16x32_bf16(v1, pb1, o[c], 0, 0, 0);
    }
    __builtin_amdgcn_s_setprio(0);

    // ---- single end-of-iter barrier: next K/V (issued ~400cy ago) landed ----
    asm volatile("s_waitcnt vmcnt(0)" ::: "memory");
    __builtin_amdgcn_s_barrier();
    asm volatile("" ::: "memory");
  }
#undef STAGEK
#undef STAGEV

  // ---- epilogue: transpose O^T -> O via per-wave LDS (reuse Ksm) ----
  short* Ol = &Ksm[0][0] + wave * 2176;
  const float invl = 1.0f / l_i;
#pragma unroll
  for (int c = 0; c < 8; ++c) {
    uint2 w;
    w.x = pack2(o[c][0] * invl, o[c][1] * invl);
    w.y = pack2(o[c][2] * invl, o[c][3] * invl);
    *(uint2*)&Ol[cl * 136 + c * 16 + 4 * g] = w;
  }
  asm volatile("s_waitcnt lgkmcnt(0)" ::: "memory");
  const int rowq = lane & 15, seg = lane >> 4;
  const short* srcl = Ol + rowq * 136 + seg * 32;
  short* dst = ao + (size_t)(b * 2048 + q0w + rowq) * 2048 + h * 128 + seg * 32;
#pragma unroll
  for (int k = 0; k < 4; ++k)
    *(bf16x8*)(dst + 8 * k) = *(const bf16x8*)(srcl + 8 * k);
}

extern "C" void kernel_launch(void* const* d_in, const int* in_sizes, int n_in,
                              void* d_out, int out_size, void* d_ws, size_t ws_size,
                              hipStream_t stream) {
  const float* x = (const float*)d_in[0];
  const float* Wq = (const float*)d_in[1];
  const float* Wk = (const float*)d_in[2];
  const float* Wv = (const float*)d_in[3];
  const float* Wo = (const float*)d_in[4];
  float* out = (float*)d_out;

  char* ws = (char*)d_ws;
  short* x_bf = (short*)ws;   ws += (size_t)4096 * 2048 * 2;
  short* wqkv_t = (short*)ws; ws += (size_t)3072 * 2048 * 2;
  short* wo_t = (short*)ws;   ws += (size_t)2048 * 2048 * 2;
  short* qkv = (short*)ws;    ws += (size_t)4096 * 3072 * 2;
  short* q_bf = (short*)ws;   ws += (size_t)2 * 16 * 2048 * 128 * 2;
  short* k_sel = (short*)ws;  ws += (size_t)2 * 4 * 1152 * 128 * 2;
  short* v_t = (short*)ws;    ws += (size_t)2 * 4 * 128 * 1152 * 2;
  short* ao = (short*)ws;     ws += (size_t)4096 * 2048 * 2;

  cvt_kernel<<<4096, 256, 0, stream>>>(x, x_bf, 1048576);
  transpose_all<<<dim3(160, 64), 256, 0, stream>>>(Wq, Wk, Wv, Wo, wqkv_t, wo_t);
  gemm_bt<1><<<dim3(24, 32), 256, 0, stream>>>(x_bf, wqkv_t, qkv, 4096, 3072, 2048);
  pp_kernel<<<25088, 256, 0, stream>>>(qkv, q_bf, k_sel, v_t);
  attn_kernel<<<1024, 256, 0, stream>>>(q_bf, k_sel, v_t, ao);
  gemm_bt<0><<<dim3(16, 32), 256, 0, stream>>>(ao, wo_t, out, 4096, 2048, 2048);
}

// Round 4
// 313.514 us; speedup vs baseline: 1.7733x; 1.0240x over previous
//
#include <hip/hip_runtime.h>
#include <hip/hip_bf16.h>
#include <math.h>

typedef __attribute__((ext_vector_type(4))) float f32x4;
typedef __attribute__((ext_vector_type(8))) short bf16x8;

#define LDSP(p)  ((__attribute__((address_space(3))) void*)(p))
#define GMEMP(p) ((const __attribute__((address_space(1))) void*)(p))

__device__ __forceinline__ short f2b(float f) {
  __hip_bfloat16 h = __float2bfloat16(f);
  return __builtin_bit_cast(short, h);
}
__device__ __forceinline__ float b2f(short s) {
  __hip_bfloat16 h = __builtin_bit_cast(__hip_bfloat16, s);
  return __bfloat162float(h);
}
__device__ __forceinline__ unsigned pack2(float a, float b) {
  return (unsigned)(unsigned short)f2b(a) | ((unsigned)(unsigned short)f2b(b) << 16);
}
__device__ __forceinline__ float exp2_fast(float x) {  // 2^x via v_exp_f32
  float r;
  asm("v_exp_f32 %0, %1" : "=v"(r) : "v"(x));
  return r;
}

// ---------------- elementwise f32 -> bf16 (8 elems/thread) ----------------
__global__ void cvt_kernel(const float* __restrict__ src, short* __restrict__ dst, int n8) {
  int i = blockIdx.x * blockDim.x + threadIdx.x;
  if (i >= n8) return;
  const float4* s4 = (const float4*)src;
  float4 a = s4[2 * i], b = s4[2 * i + 1];
  bf16x8 o;
  o[0] = f2b(a.x); o[1] = f2b(a.y); o[2] = f2b(a.z); o[3] = f2b(a.w);
  o[4] = f2b(b.x); o[5] = f2b(b.y); o[6] = f2b(b.z); o[7] = f2b(b.w);
  *(bf16x8*)(dst + (size_t)i * 8) = o;
}

// ---------------- all 4 weight transposes in one kernel -------------------
__global__ void transpose_all(const float* __restrict__ Wq, const float* __restrict__ Wk,
                              const float* __restrict__ Wv, const float* __restrict__ Wo,
                              short* __restrict__ wqkv_t, short* __restrict__ wo_t) {
  __shared__ float tile[32][33];
  int gx = blockIdx.x;
  const float* src; short* dst; int cols, cx;
  if (gx < 64)       { src = Wq; dst = wqkv_t;                        cols = 2048; cx = gx; }
  else if (gx < 80)  { src = Wk; dst = wqkv_t + (size_t)2048 * 2048;  cols = 512;  cx = gx - 64; }
  else if (gx < 96)  { src = Wv; dst = wqkv_t + (size_t)2560 * 2048;  cols = 512;  cx = gx - 80; }
  else               { src = Wo; dst = wo_t;                          cols = 2048; cx = gx - 96; }
  int c0 = cx * 32, r0 = blockIdx.y * 32;
  int tx = threadIdx.x & 31, ty = threadIdx.x >> 5;
  for (int i = ty; i < 32; i += 8)
    tile[i][tx] = src[(size_t)(r0 + i) * cols + c0 + tx];
  __syncthreads();
  for (int i = ty; i < 32; i += 8)
    dst[(size_t)(c0 + i) * 2048 + r0 + tx] = f2b(tile[tx][i]);
}

// ---------------- bf16 GEMM: C = A[M][K] @ B[K][N], Bt = B^T [N][K] -------
// 128x128 tile, BK=32, 4 waves. Ring-3 LDS, counted vmcnt(4), raw barrier,
// XOR swizzle col^=((row>>1)&3)<<3 (pre-swizzled source + swizzled read).
template <int OUTBF>
__global__ __launch_bounds__(256) void gemm_bt(const short* __restrict__ A,
                                               const short* __restrict__ Bt,
                                               void* __restrict__ Cv,
                                               int M, int N, int K) {
  __shared__ alignas(16) short As[3][128 * 32];
  __shared__ alignas(16) short Bs[3][128 * 32];
  const int m0 = blockIdx.y * 128, n0 = blockIdx.x * 128;
  const int wave = threadIdx.x >> 6, lane = threadIdx.x & 63;
  const int g = lane >> 4, cl = lane & 15;
  const int wr = (wave >> 1) * 64, wc = (wave & 1) * 64;
  const int tid = threadIdx.x;
  f32x4 acc[4][4];
#pragma unroll
  for (int i = 0; i < 4; ++i)
#pragma unroll
    for (int j = 0; j < 4; ++j) acc[i][j] = (f32x4){0.f, 0.f, 0.f, 0.f};

  const int e0 = tid * 8;
#define STAGE(kt, s)                                                                        \
  {                                                                                         \
    _Pragma("unroll") for (int c = 0; c < 2; ++c) {                                         \
      int e = c * 2048 + e0;                                                                \
      int r = e >> 5;                                                                       \
      int j = (e >> 3) & 3;                                                                 \
      int col = (kt) + 8 * (j ^ ((r >> 1) & 3));                                            \
      __builtin_amdgcn_global_load_lds(GMEMP(A + (size_t)(m0 + r) * K + col),               \
                                       LDSP(&As[s][e]), 16, 0, 0);                          \
      __builtin_amdgcn_global_load_lds(GMEMP(Bt + (size_t)(n0 + r) * K + col),              \
                                       LDSP(&Bs[s][e]), 16, 0, 0);                          \
    }                                                                                       \
  }

  const int nkt = K >> 5;
  STAGE(0, 0);
  STAGE(32, 1);
  asm volatile("s_waitcnt vmcnt(4)" ::: "memory");
  __builtin_amdgcn_s_barrier();
  asm volatile("" ::: "memory");

  int s = 0;
  for (int t = 0; t < nkt; ++t) {
    if (t + 2 < nkt) {
      int s2 = s + 2; if (s2 >= 3) s2 -= 3;
      STAGE((t + 2) << 5, s2);
    }
    bf16x8 af[4], bfr[4];
#pragma unroll
    for (int i = 0; i < 4; ++i) {
      int R = wr + 16 * i + cl;
      af[i] = *(const bf16x8*)&As[s][R * 32 + 8 * (g ^ ((R >> 1) & 3))];
    }
#pragma unroll
    for (int j = 0; j < 4; ++j) {
      int R = wc + 16 * j + cl;
      bfr[j] = *(const bf16x8*)&Bs[s][R * 32 + 8 * (g ^ ((R >> 1) & 3))];
    }
    __builtin_amdgcn_s_setprio(1);
#pragma unroll
    for (int i = 0; i < 4; ++i)
#pragma unroll
      for (int j = 0; j < 4; ++j)
        acc[i][j] = __builtin_amdgcn_mfma_f32_16x16x32_bf16(af[i], bfr[j], acc[i][j], 0, 0, 0);
    __builtin_amdgcn_s_setprio(0);
    asm volatile("s_waitcnt vmcnt(4)" ::: "memory");
    __builtin_amdgcn_s_barrier();
    asm volatile("" ::: "memory");
    if (++s >= 3) s -= 3;
  }
#undef STAGE
#pragma unroll
  for (int i = 0; i < 4; ++i)
#pragma unroll
    for (int j = 0; j < 4; ++j)
#pragma unroll
      for (int r = 0; r < 4; ++r) {
        int row = m0 + wr + 16 * i + 4 * g + r;
        int col = n0 + wc + 16 * j + cl;
        if (OUTBF)
          ((short*)Cv)[(size_t)row * N + col] = f2b(acc[i][j][r]);
        else
          ((float*)Cv)[(size_t)row * N + col] = acc[i][j][r];
      }
}

// ---------------- fused postprocess: rope_q | rope_k | vsel ---------------
// NOTE: q is pre-scaled by 1/sqrt(128) * log2(e) so attention's QK^T lands
// directly in exp2 domain.
__global__ void pp_kernel(const short* __restrict__ qkv, short* __restrict__ qb,
                          short* __restrict__ ksel, short* __restrict__ vt) {
  int blk = blockIdx.x;
  if (blk < 16384) {
    // rope_q (+ scale fold)
    const float SCL = 0.08838834764831845f * 1.4426950408889634f;
    int tid = blk * 256 + threadIdx.x;
    int i = tid & 63;
    int h = (tid >> 6) & 15;
    int row = tid >> 10;
    int t = row & 2047;
    int b = row >> 11;
    unsigned u = *(const unsigned*)(qkv + (size_t)row * 3072 + h * 128 + 2 * i);
    float x1 = b2f((short)(u & 0xffff));
    float x2 = b2f((short)(u >> 16));
    float inv = exp2f(-0.20762050593046f * (float)i);
    float ang = (float)t * inv;
    float sn, cs;
    __sincosf(ang, &sn, &cs);
    unsigned w = pack2((x1 * cs - x2 * sn) * SCL, (x1 * sn + x2 * cs) * SCL);
    *(unsigned*)(qb + (size_t)((b * 16 + h) * 2048 + t) * 128 + 2 * i) = w;
  } else if (blk < 16384 + 4096) {
    // rope_k + window select
    int tid = (blk - 16384) * 256 + threadIdx.x;
    int i = tid & 63;
    int kvh = (tid >> 6) & 3;
    int row = tid >> 8;
    int t = row & 2047;
    int b = row >> 11;
    int idx = t < 128 ? t : (t >= 1024 ? t - 896 : -1);
    if (idx < 0) return;
    unsigned u = *(const unsigned*)(qkv + (size_t)row * 3072 + 2048 + kvh * 128 + 2 * i);
    float x1 = b2f((short)(u & 0xffff));
    float x2 = b2f((short)(u >> 16));
    float inv = exp2f(-0.20762050593046f * (float)i);
    float ang = (float)t * inv;
    float sn, cs;
    __sincosf(ang, &sn, &cs);
    unsigned w = pack2(x1 * cs - x2 * sn, x1 * sn + x2 * cs);
    *(unsigned*)(ksel + (size_t)((b * 4 + kvh) * 1152 + idx) * 128 + 2 * i) = w;
  } else {
    // V select + transpose
    int tid = (blk - 20480) * 256 + threadIdx.x;
    int idx = tid % 1152;
    int rest = tid / 1152;
    int d = rest & 127;
    int kvh = (rest >> 7) & 3;
    int b = rest >> 9;
    int t = idx < 128 ? idx : idx + 896;
    vt[(size_t)((b * 4 + kvh) * 128 + d) * 1152 + idx] =
        qkv[(size_t)(b * 2048 + t) * 3072 + 2560 + kvh * 128 + d];
  }
}

// ---------------- attention v4 ------------------------------------------
// Same sync structure as v3 (proven): K/V double-buffered, prefetch at iter
// top, single end-of-iter barrier. Changes: exp2-domain softmax (Q
// pre-scaled), mask only in tail iters, defer-max rescale (THR=8),
// Psm layout [g][j][r] (conflict-free b128 writes / b64 reads).
__global__ __launch_bounds__(256) void attn_kernel(const short* __restrict__ qb,
                                                   const short* __restrict__ ksel,
                                                   const short* __restrict__ vt,
                                                   short* __restrict__ ao) {
  __shared__ alignas(16) short Ksm[2][8192];   // [64 keys][128 d], swizzled
  __shared__ alignas(16) short Vsm[2][8192];   // [128 d][64 keys], swizzled
  __shared__ alignas(16) short Psm[4][16][72]; // per-wave P, order [g][j][r]

  const int blk = blockIdx.x;
  const int qt = 31 - (blk >> 5);              // heavy tiles first
  const int h = blk & 15, b = (blk >> 4) & 1;
  const int kv = h >> 2;
  const int wave = threadIdx.x >> 6, lane = threadIdx.x & 63;
  const int g = lane >> 4, cl = lane & 15;
  const int q0w = qt * 64 + wave * 16;
  const int qi = q0w + cl;
  const int niter = (qt + 1 < 18) ? (qt + 1) : 18;
  const int nfull = (qt < 18) ? qt : 18;       // iters with no masking needed

  const short* kselb = ksel + (size_t)(b * 4 + kv) * 1152 * 128;
  const short* vtb = vt + (size_t)(b * 4 + kv) * 128 * 1152;

  const short* qrow = qb + (size_t)((b * 16 + h) * 2048 + qi) * 128;
  bf16x8 qf[4];
#pragma unroll
  for (int d = 0; d < 4; ++d) qf[d] = *(const bf16x8*)(qrow + d * 32 + 8 * g);

  f32x4 o[8];
#pragma unroll
  for (int c = 0; c < 8; ++c) o[c] = (f32x4){0.f, 0.f, 0.f, 0.f};
  float m_i = -1e30f, l_i = 0.f;

#define STAGEK(kk0, buf)                                                                  \
  {                                                                                       \
    _Pragma("unroll") for (int i = 0; i < 4; ++i) {                                       \
      int base = i * 2048 + wave * 512;                                                   \
      int Lel = base + lane * 8;                                                          \
      int kr = Lel >> 7;                                                                  \
      int kc = (Lel & 127) ^ ((kr & 7) << 3);                                             \
      __builtin_amdgcn_global_load_lds(GMEMP(kselb + (size_t)((kk0) + kr) * 128 + kc),    \
                                       LDSP(&Ksm[buf][base]), 16, 0, 0);                  \
    }                                                                                     \
  }
#define STAGEV(kk0, buf)                                                                  \
  {                                                                                       \
    _Pragma("unroll") for (int i = 0; i < 4; ++i) {                                       \
      int base = i * 2048 + wave * 512;                                                   \
      int Lel = base + lane * 8;                                                          \
      int vr = Lel >> 6;                                                                  \
      int vc = (Lel & 63) ^ ((vr & 7) << 3);                                              \
      __builtin_amdgcn_global_load_lds(GMEMP(vtb + (size_t)vr * 1152 + (kk0) + vc),       \
                                       LDSP(&Vsm[buf][base]), 16, 0, 0);                  \
    }                                                                                     \
  }

  STAGEK(0, 0);
  STAGEV(0, 0);
  asm volatile("s_waitcnt vmcnt(0)" ::: "memory");
  __builtin_amdgcn_s_barrier();
  asm volatile("" ::: "memory");

  for (int t = 0; t < niter; ++t) {
    const int cur = t & 1;
    const int kk0 = t * 64;
    if (t + 1 < niter) {
      STAGEK(kk0 + 64, cur ^ 1);
      STAGEV(kk0 + 64, cur ^ 1);
    }

    // ---- QK^T (swapped): lane owns q=qi; S already in exp2 domain ----
    f32x4 sf[4];
#pragma unroll
    for (int j = 0; j < 4; ++j) sf[j] = (f32x4){0.f, 0.f, 0.f, 0.f};
    const short* kb = &Ksm[cur][0];
    const int sw = (cl & 7) << 3;
    __builtin_amdgcn_s_setprio(1);
#pragma unroll
    for (int j = 0; j < 4; ++j) {
      const int rs = (16 * j + cl) * 128;
#pragma unroll
      for (int d = 0; d < 4; ++d) {
        bf16x8 kf = *(const bf16x8*)&kb[rs + ((d * 32 + 8 * g) ^ sw)];
        sf[j] = __builtin_amdgcn_mfma_f32_16x16x32_bf16(kf, qf[d], sf[j], 0, 0, 0);
      }
    }
    __builtin_amdgcn_s_setprio(0);

    // ---- mask only in tail iterations (wave-uniform branch) ----
    if (t >= nfull) {
#pragma unroll
      for (int j = 0; j < 4; ++j)
#pragma unroll
        for (int r = 0; r < 4; ++r) {
          int key = kk0 + 16 * j + 4 * g + r;
          sf[j][r] = (key <= qi) ? sf[j][r] : -3.0e38f;
        }
    }

    // ---- row max (tree, v_max3-friendly) + cross-group reduce ----
    float ma = fmaxf(fmaxf(fmaxf(sf[0][0], sf[0][1]), sf[0][2]), sf[0][3]);
    float mb = fmaxf(fmaxf(fmaxf(sf[1][0], sf[1][1]), sf[1][2]), sf[1][3]);
    float mc = fmaxf(fmaxf(fmaxf(sf[2][0], sf[2][1]), sf[2][2]), sf[2][3]);
    float md = fmaxf(fmaxf(fmaxf(sf[3][0], sf[3][1]), sf[3][2]), sf[3][3]);
    float mx = fmaxf(fmaxf(ma, mb), fmaxf(mc, md));
    mx = fmaxf(mx, __shfl_xor(mx, 16));
    mx = fmaxf(mx, __shfl_xor(mx, 32));

    // ---- defer-max: rescale only when max grew by > 8 (exp2 domain) ----
    if (!__all(mx <= m_i + 8.0f)) {
      const float mnew = fmaxf(m_i, mx);
      const float alpha = exp2_fast(m_i - mnew);
      m_i = mnew;
      l_i *= alpha;
#pragma unroll
      for (int c = 0; c < 8; ++c)
#pragma unroll
        for (int r = 0; r < 4; ++r) o[c][r] *= alpha;
    }

    // ---- p = 2^(s - m); sum tree; store Psm[g-major] ----
    float p[4][4];
#pragma unroll
    for (int j = 0; j < 4; ++j)
#pragma unroll
      for (int r = 0; r < 4; ++r) p[j][r] = exp2_fast(sf[j][r] - m_i);
    float ls = ((p[0][0] + p[0][1]) + (p[0][2] + p[0][3])) +
               ((p[1][0] + p[1][1]) + (p[1][2] + p[1][3])) +
               ((p[2][0] + p[2][1]) + (p[2][2] + p[2][3])) +
               ((p[3][0] + p[3][1]) + (p[3][2] + p[3][3]));
    ls += __shfl_xor(ls, 16);
    ls += __shfl_xor(ls, 32);
    l_i += ls;
    uint4 wA, wB;
    wA.x = pack2(p[0][0], p[0][1]); wA.y = pack2(p[0][2], p[0][3]);
    wA.z = pack2(p[1][0], p[1][1]); wA.w = pack2(p[1][2], p[1][3]);
    wB.x = pack2(p[2][0], p[2][1]); wB.y = pack2(p[2][2], p[2][3]);
    wB.z = pack2(p[3][0], p[3][1]); wB.w = pack2(p[3][2], p[3][3]);
    *(uint4*)&Psm[wave][cl][16 * g] = wA;
    *(uint4*)&Psm[wave][cl][16 * g + 8] = wB;

    // ---- PV (swapped): read P fragments [gsrc][j][r] ----
    asm volatile("s_waitcnt lgkmcnt(0)" ::: "memory");
    const int S0 = 32 * (g & 1) + 4 * (g >> 1);
    uint2 a0 = *(const uint2*)&Psm[wave][cl][S0];
    uint2 a1 = *(const uint2*)&Psm[wave][cl][S0 + 16];
    uint2 b0 = *(const uint2*)&Psm[wave][cl][S0 + 8];
    uint2 b1 = *(const uint2*)&Psm[wave][cl][S0 + 24];
    uint4 u0; u0.x = a0.x; u0.y = a0.y; u0.z = a1.x; u0.w = a1.y;
    uint4 u1; u1.x = b0.x; u1.y = b0.y; u1.z = b1.x; u1.w = b1.y;
    bf16x8 pb0 = __builtin_bit_cast(bf16x8, u0);
    bf16x8 pb1 = __builtin_bit_cast(bf16x8, u1);
    const short* vb = &Vsm[cur][0];
    __builtin_amdgcn_s_setprio(1);
#pragma unroll
    for (int c = 0; c < 8; ++c) {
      const int rvs = (c * 16 + cl) * 64;
      bf16x8 v0 = *(const bf16x8*)&vb[rvs + ((8 * g) ^ sw)];
      bf16x8 v1 = *(const bf16x8*)&vb[rvs + ((32 + 8 * g) ^ sw)];
      o[c] = __builtin_amdgcn_mfma_f32_16x16x32_bf16(v0, pb0, o[c], 0, 0, 0);
      o[c] = __builtin_amdgcn_mfma_f32_16x16x32_bf16(v1, pb1, o[c], 0, 0, 0);
    }
    __builtin_amdgcn_s_setprio(0);

    // ---- single end-of-iter barrier: next K/V landed ----
    asm volatile("s_waitcnt vmcnt(0)" ::: "memory");
    __builtin_amdgcn_s_barrier();
    asm volatile("" ::: "memory");
  }
#undef STAGEK
#undef STAGEV

  // ---- epilogue: transpose O^T -> O via per-wave LDS (reuse Ksm) ----
  short* Ol = &Ksm[0][0] + wave * 2176;
  const float invl = 1.0f / l_i;
#pragma unroll
  for (int c = 0; c < 8; ++c) {
    uint2 w;
    w.x = pack2(o[c][0] * invl, o[c][1] * invl);
    w.y = pack2(o[c][2] * invl, o[c][3] * invl);
    *(uint2*)&Ol[cl * 136 + c * 16 + 4 * g] = w;
  }
  asm volatile("s_waitcnt lgkmcnt(0)" ::: "memory");
  const int rowq = lane & 15, seg = lane >> 4;
  const short* srcl = Ol + rowq * 136 + seg * 32;
  short* dst = ao + (size_t)(b * 2048 + q0w + rowq) * 2048 + h * 128 + seg * 32;
#pragma unroll
  for (int k = 0; k < 4; ++k)
    *(bf16x8*)(dst + 8 * k) = *(const bf16x8*)(srcl + 8 * k);
}

extern "C" void kernel_launch(void* const* d_in, const int* in_sizes, int n_in,
                              void* d_out, int out_size, void* d_ws, size_t ws_size,
                              hipStream_t stream) {
  const float* x = (const float*)d_in[0];
  const float* Wq = (const float*)d_in[1];
  const float* Wk = (const float*)d_in[2];
  const float* Wv = (const float*)d_in[3];
  const float* Wo = (const float*)d_in[4];
  float* out = (float*)d_out;

  char* ws = (char*)d_ws;
  short* x_bf = (short*)ws;   ws += (size_t)4096 * 2048 * 2;
  short* wqkv_t = (short*)ws; ws += (size_t)3072 * 2048 * 2;
  short* wo_t = (short*)ws;   ws += (size_t)2048 * 2048 * 2;
  short* qkv = (short*)ws;    ws += (size_t)4096 * 3072 * 2;
  short* q_bf = (short*)ws;   ws += (size_t)2 * 16 * 2048 * 128 * 2;
  short* k_sel = (short*)ws;  ws += (size_t)2 * 4 * 1152 * 128 * 2;
  short* v_t = (short*)ws;    ws += (size_t)2 * 4 * 128 * 1152 * 2;
  short* ao = (short*)ws;     ws += (size_t)4096 * 2048 * 2;

  cvt_kernel<<<4096, 256, 0, stream>>>(x, x_bf, 1048576);
  transpose_all<<<dim3(160, 64), 256, 0, stream>>>(Wq, Wk, Wv, Wo, wqkv_t, wo_t);
  gemm_bt<1><<<dim3(24, 32), 256, 0, stream>>>(x_bf, wqkv_t, qkv, 4096, 3072, 2048);
  pp_kernel<<<25088, 256, 0, stream>>>(qkv, q_bf, k_sel, v_t);
  attn_kernel<<<1024, 256, 0, stream>>>(q_bf, k_sel, v_t, ao);
  gemm_bt<0><<<dim3(16, 32), 256, 0, stream>>>(ao, wo_t, out, 4096, 2048, 2048);
}

// Round 5
// 300.341 us; speedup vs baseline: 1.8511x; 1.0439x over previous
//
#include <hip/hip_runtime.h>
#include <hip/hip_bf16.h>
#include <math.h>

typedef __attribute__((ext_vector_type(4))) float f32x4;
typedef __attribute__((ext_vector_type(8))) short bf16x8;

#define LDSP(p)  ((__attribute__((address_space(3))) void*)(p))
#define GMEMP(p) ((const __attribute__((address_space(1))) void*)(p))

__device__ __forceinline__ short f2b(float f) {
  __hip_bfloat16 h = __float2bfloat16(f);
  return __builtin_bit_cast(short, h);
}
__device__ __forceinline__ float b2f(short s) {
  __hip_bfloat16 h = __builtin_bit_cast(__hip_bfloat16, s);
  return __bfloat162float(h);
}
__device__ __forceinline__ unsigned pack2(float a, float b) {
  return (unsigned)(unsigned short)f2b(a) | ((unsigned)(unsigned short)f2b(b) << 16);
}
__device__ __forceinline__ float exp2_fast(float x) {  // 2^x via v_exp_f32
  float r;
  asm("v_exp_f32 %0, %1" : "=v"(r) : "v"(x));
  return r;
}

// ---------------- elementwise f32 -> bf16 (8 elems/thread) ----------------
__global__ void cvt_kernel(const float* __restrict__ src, short* __restrict__ dst, int n8) {
  int i = blockIdx.x * blockDim.x + threadIdx.x;
  if (i >= n8) return;
  const float4* s4 = (const float4*)src;
  float4 a = s4[2 * i], b = s4[2 * i + 1];
  bf16x8 o;
  o[0] = f2b(a.x); o[1] = f2b(a.y); o[2] = f2b(a.z); o[3] = f2b(a.w);
  o[4] = f2b(b.x); o[5] = f2b(b.y); o[6] = f2b(b.z); o[7] = f2b(b.w);
  *(bf16x8*)(dst + (size_t)i * 8) = o;
}

// ---------------- all 4 weight transposes in one kernel -------------------
__global__ void transpose_all(const float* __restrict__ Wq, const float* __restrict__ Wk,
                              const float* __restrict__ Wv, const float* __restrict__ Wo,
                              short* __restrict__ wqkv_t, short* __restrict__ wo_t) {
  __shared__ float tile[32][33];
  int gx = blockIdx.x;
  const float* src; short* dst; int cols, cx;
  if (gx < 64)       { src = Wq; dst = wqkv_t;                        cols = 2048; cx = gx; }
  else if (gx < 80)  { src = Wk; dst = wqkv_t + (size_t)2048 * 2048;  cols = 512;  cx = gx - 64; }
  else if (gx < 96)  { src = Wv; dst = wqkv_t + (size_t)2560 * 2048;  cols = 512;  cx = gx - 80; }
  else               { src = Wo; dst = wo_t;                          cols = 2048; cx = gx - 96; }
  int c0 = cx * 32, r0 = blockIdx.y * 32;
  int tx = threadIdx.x & 31, ty = threadIdx.x >> 5;
  for (int i = ty; i < 32; i += 8)
    tile[i][tx] = src[(size_t)(r0 + i) * cols + c0 + tx];
  __syncthreads();
  for (int i = ty; i < 32; i += 8)
    dst[(size_t)(c0 + i) * 2048 + r0 + tx] = f2b(tile[tx][i]);
}

// ---------------- bf16 GEMM: C = A[M][K] @ B[K][N], Bt = B^T [N][K] -------
// 128x128 tile, BK=32, 4 waves. Ring-3 LDS, counted vmcnt(4), raw barrier,
// XOR swizzle col^=((row>>1)&3)<<3 (pre-swizzled source + swizzled read).
template <int OUTBF>
__global__ __launch_bounds__(256) void gemm_bt(const short* __restrict__ A,
                                               const short* __restrict__ Bt,
                                               void* __restrict__ Cv,
                                               int M, int N, int K) {
  __shared__ alignas(16) short As[3][128 * 32];
  __shared__ alignas(16) short Bs[3][128 * 32];
  const int m0 = blockIdx.y * 128, n0 = blockIdx.x * 128;
  const int wave = threadIdx.x >> 6, lane = threadIdx.x & 63;
  const int g = lane >> 4, cl = lane & 15;
  const int wr = (wave >> 1) * 64, wc = (wave & 1) * 64;
  const int tid = threadIdx.x;
  f32x4 acc[4][4];
#pragma unroll
  for (int i = 0; i < 4; ++i)
#pragma unroll
    for (int j = 0; j < 4; ++j) acc[i][j] = (f32x4){0.f, 0.f, 0.f, 0.f};

  const int e0 = tid * 8;
#define STAGE(kt, s)                                                                        \
  {                                                                                         \
    _Pragma("unroll") for (int c = 0; c < 2; ++c) {                                         \
      int e = c * 2048 + e0;                                                                \
      int r = e >> 5;                                                                       \
      int j = (e >> 3) & 3;                                                                 \
      int col = (kt) + 8 * (j ^ ((r >> 1) & 3));                                            \
      __builtin_amdgcn_global_load_lds(GMEMP(A + (size_t)(m0 + r) * K + col),               \
                                       LDSP(&As[s][e]), 16, 0, 0);                          \
      __builtin_amdgcn_global_load_lds(GMEMP(Bt + (size_t)(n0 + r) * K + col),              \
                                       LDSP(&Bs[s][e]), 16, 0, 0);                          \
    }                                                                                       \
  }

  const int nkt = K >> 5;
  STAGE(0, 0);
  STAGE(32, 1);
  asm volatile("s_waitcnt vmcnt(4)" ::: "memory");
  __builtin_amdgcn_s_barrier();
  asm volatile("" ::: "memory");

  int s = 0;
  for (int t = 0; t < nkt; ++t) {
    if (t + 2 < nkt) {
      int s2 = s + 2; if (s2 >= 3) s2 -= 3;
      STAGE((t + 2) << 5, s2);
    }
    bf16x8 af[4], bfr[4];
#pragma unroll
    for (int i = 0; i < 4; ++i) {
      int R = wr + 16 * i + cl;
      af[i] = *(const bf16x8*)&As[s][R * 32 + 8 * (g ^ ((R >> 1) & 3))];
    }
#pragma unroll
    for (int j = 0; j < 4; ++j) {
      int R = wc + 16 * j + cl;
      bfr[j] = *(const bf16x8*)&Bs[s][R * 32 + 8 * (g ^ ((R >> 1) & 3))];
    }
    __builtin_amdgcn_s_setprio(1);
#pragma unroll
    for (int i = 0; i < 4; ++i)
#pragma unroll
      for (int j = 0; j < 4; ++j)
        acc[i][j] = __builtin_amdgcn_mfma_f32_16x16x32_bf16(af[i], bfr[j], acc[i][j], 0, 0, 0);
    __builtin_amdgcn_s_setprio(0);
    asm volatile("s_waitcnt vmcnt(4)" ::: "memory");
    __builtin_amdgcn_s_barrier();
    asm volatile("" ::: "memory");
    if (++s >= 3) s -= 3;
  }
#undef STAGE
#pragma unroll
  for (int i = 0; i < 4; ++i)
#pragma unroll
    for (int j = 0; j < 4; ++j)
#pragma unroll
      for (int r = 0; r < 4; ++r) {
        int row = m0 + wr + 16 * i + 4 * g + r;
        int col = n0 + wc + 16 * j + cl;
        if (OUTBF)
          ((short*)Cv)[(size_t)row * N + col] = f2b(acc[i][j][r]);
        else
          ((float*)Cv)[(size_t)row * N + col] = acc[i][j][r];
      }
}

// ---------------- fused postprocess: rope_q | rope_k | vsel ---------------
// NOTE: q is pre-scaled by 1/sqrt(128) * log2(e) so attention's QK^T lands
// directly in exp2 domain.
__global__ void pp_kernel(const short* __restrict__ qkv, short* __restrict__ qb,
                          short* __restrict__ ksel, short* __restrict__ vt) {
  int blk = blockIdx.x;
  if (blk < 16384) {
    // rope_q (+ scale fold)
    const float SCL = 0.08838834764831845f * 1.4426950408889634f;
    int tid = blk * 256 + threadIdx.x;
    int i = tid & 63;
    int h = (tid >> 6) & 15;
    int row = tid >> 10;
    int t = row & 2047;
    int b = row >> 11;
    unsigned u = *(const unsigned*)(qkv + (size_t)row * 3072 + h * 128 + 2 * i);
    float x1 = b2f((short)(u & 0xffff));
    float x2 = b2f((short)(u >> 16));
    float inv = exp2f(-0.20762050593046f * (float)i);
    float ang = (float)t * inv;
    float sn, cs;
    __sincosf(ang, &sn, &cs);
    unsigned w = pack2((x1 * cs - x2 * sn) * SCL, (x1 * sn + x2 * cs) * SCL);
    *(unsigned*)(qb + (size_t)((b * 16 + h) * 2048 + t) * 128 + 2 * i) = w;
  } else if (blk < 16384 + 4096) {
    // rope_k + window select
    int tid = (blk - 16384) * 256 + threadIdx.x;
    int i = tid & 63;
    int kvh = (tid >> 6) & 3;
    int row = tid >> 8;
    int t = row & 2047;
    int b = row >> 11;
    int idx = t < 128 ? t : (t >= 1024 ? t - 896 : -1);
    if (idx < 0) return;
    unsigned u = *(const unsigned*)(qkv + (size_t)row * 3072 + 2048 + kvh * 128 + 2 * i);
    float x1 = b2f((short)(u & 0xffff));
    float x2 = b2f((short)(u >> 16));
    float inv = exp2f(-0.20762050593046f * (float)i);
    float ang = (float)t * inv;
    float sn, cs;
    __sincosf(ang, &sn, &cs);
    unsigned w = pack2(x1 * cs - x2 * sn, x1 * sn + x2 * cs);
    *(unsigned*)(ksel + (size_t)((b * 4 + kvh) * 1152 + idx) * 128 + 2 * i) = w;
  } else {
    // V select + transpose
    int tid = (blk - 20480) * 256 + threadIdx.x;
    int idx = tid % 1152;
    int rest = tid / 1152;
    int d = rest & 127;
    int kvh = (rest >> 7) & 3;
    int b = rest >> 9;
    int t = idx < 128 ? idx : idx + 896;
    vt[(size_t)((b * 4 + kvh) * 128 + d) * 1152 + idx] =
        qkv[(size_t)(b * 2048 + t) * 3072 + 2560 + kvh * 128 + d];
  }
}

// ---------------- attention v5 ------------------------------------------
// block = (b,h,qtile of 128 rows), 8 waves x 16 q-rows, 64-key chunks.
// K double-buffered LDS; V single-buffered (staged at iter top, consumed
// after softmax); per-wave P in LDS; one shared 66KB arena -> 2 blocks/CU
// = 16 waves/CU (4/SIMD). Inner math identical to v4 (exp2 domain,
// defer-max, tail-only masking, XOR swizzles).
__global__ __launch_bounds__(512, 4) void attn_kernel(const short* __restrict__ qb,
                                                      const short* __restrict__ ksel,
                                                      const short* __restrict__ vt,
                                                      short* __restrict__ ao) {
  __shared__ alignas(16) short SM[33792];  // K:2x8192 | V:8192 | P:8x16x72
  short* Vsm = SM + 16384;
  short* Psm = SM + 24576;

  const int blk = blockIdx.x;                  // 512 blocks
  const int qt = 15 - (blk >> 5);              // heavy tiles first
  const int h = blk & 15, b = (blk >> 4) & 1;
  const int kv = h >> 2;
  const int wave = threadIdx.x >> 6, lane = threadIdx.x & 63;
  const int g = lane >> 4, cl = lane & 15;
  const int q0w = qt * 128 + wave * 16;
  const int qi = q0w + cl;
  const int niter = (2 * qt + 2 < 18) ? (2 * qt + 2) : 18;
  const int nfull = (2 * qt < 18) ? (2 * qt) : 18;

  const short* kselb = ksel + (size_t)(b * 4 + kv) * 1152 * 128;
  const short* vtb = vt + (size_t)(b * 4 + kv) * 128 * 1152;

  const short* qrow = qb + (size_t)((b * 16 + h) * 2048 + qi) * 128;
  bf16x8 qf[4];
#pragma unroll
  for (int d = 0; d < 4; ++d) qf[d] = *(const bf16x8*)(qrow + d * 32 + 8 * g);

  f32x4 o[8];
#pragma unroll
  for (int c = 0; c < 8; ++c) o[c] = (f32x4){0.f, 0.f, 0.f, 0.f};
  float m_i = -1e30f, l_i = 0.f;

  // 512 threads stage 8192 shorts in 2 passes of 16B/lane.
#define STAGEK(kk0, buf)                                                                  \
  {                                                                                       \
    _Pragma("unroll") for (int i = 0; i < 2; ++i) {                                       \
      int base = i * 4096 + wave * 512;                                                   \
      int Lel = base + lane * 8;                                                          \
      int kr = Lel >> 7;                                                                  \
      int kc = (Lel & 127) ^ ((kr & 7) << 3);                                             \
      __builtin_amdgcn_global_load_lds(GMEMP(kselb + (size_t)((kk0) + kr) * 128 + kc),    \
                                       LDSP(SM + (buf) * 8192 + base), 16, 0, 0);         \
    }                                                                                     \
  }
#define STAGEV(kk0)                                                                       \
  {                                                                                       \
    _Pragma("unroll") for (int i = 0; i < 2; ++i) {                                       \
      int base = i * 4096 + wave * 512;                                                   \
      int Lel = base + lane * 8;                                                          \
      int vr = Lel >> 6;                                                                  \
      int vc = (Lel & 63) ^ ((vr & 7) << 3);                                              \
      __builtin_amdgcn_global_load_lds(GMEMP(vtb + (size_t)vr * 1152 + (kk0) + vc),       \
                                       LDSP(Vsm + base), 16, 0, 0);                       \
    }                                                                                     \
  }

  STAGEK(0, 0);
  STAGEV(0);
  asm volatile("s_waitcnt vmcnt(0)" ::: "memory");
  __builtin_amdgcn_s_barrier();
  asm volatile("" ::: "memory");

  short* Pw = Psm + wave * 1152 + cl * 72;  // this lane's P row base

  for (int t = 0; t < niter; ++t) {
    const int cur = t & 1;
    const int kk0 = t * 64;
    if (t > 0) STAGEV(kk0);                    // V(t) into single buffer
    const bool lastk = (t + 1 >= niter);
    if (!lastk) STAGEK(kk0 + 64, cur ^ 1);     // prefetch K(t+1)

    // ---- QK^T (swapped): lane owns q=qi; S already in exp2 domain ----
    f32x4 sf[4];
#pragma unroll
    for (int j = 0; j < 4; ++j) sf[j] = (f32x4){0.f, 0.f, 0.f, 0.f};
    const short* kb = SM + cur * 8192;
    const int sw = (cl & 7) << 3;
    __builtin_amdgcn_s_setprio(1);
#pragma unroll
    for (int j = 0; j < 4; ++j) {
      const int rs = (16 * j + cl) * 128;
#pragma unroll
      for (int d = 0; d < 4; ++d) {
        bf16x8 kf = *(const bf16x8*)&kb[rs + ((d * 32 + 8 * g) ^ sw)];
        sf[j] = __builtin_amdgcn_mfma_f32_16x16x32_bf16(kf, qf[d], sf[j], 0, 0, 0);
      }
    }
    __builtin_amdgcn_s_setprio(0);

    // ---- mask only in tail iterations (wave-uniform branch) ----
    if (t >= nfull) {
#pragma unroll
      for (int j = 0; j < 4; ++j)
#pragma unroll
        for (int r = 0; r < 4; ++r) {
          int key = kk0 + 16 * j + 4 * g + r;
          sf[j][r] = (key <= qi) ? sf[j][r] : -3.0e38f;
        }
    }

    // ---- row max + cross-group reduce ----
    float ma = fmaxf(fmaxf(fmaxf(sf[0][0], sf[0][1]), sf[0][2]), sf[0][3]);
    float mb = fmaxf(fmaxf(fmaxf(sf[1][0], sf[1][1]), sf[1][2]), sf[1][3]);
    float mc = fmaxf(fmaxf(fmaxf(sf[2][0], sf[2][1]), sf[2][2]), sf[2][3]);
    float md = fmaxf(fmaxf(fmaxf(sf[3][0], sf[3][1]), sf[3][2]), sf[3][3]);
    float mx = fmaxf(fmaxf(ma, mb), fmaxf(mc, md));
    mx = fmaxf(mx, __shfl_xor(mx, 16));
    mx = fmaxf(mx, __shfl_xor(mx, 32));

    // ---- defer-max: rescale only when max grew by > 8 (exp2 domain) ----
    if (!__all(mx <= m_i + 8.0f)) {
      const float mnew = fmaxf(m_i, mx);
      const float alpha = exp2_fast(m_i - mnew);
      m_i = mnew;
      l_i *= alpha;
#pragma unroll
      for (int c = 0; c < 8; ++c)
#pragma unroll
        for (int r = 0; r < 4; ++r) o[c][r] *= alpha;
    }

    // ---- p = 2^(s - m); sum tree; store P (g-major layout) ----
    float p[4][4];
#pragma unroll
    for (int j = 0; j < 4; ++j)
#pragma unroll
      for (int r = 0; r < 4; ++r) p[j][r] = exp2_fast(sf[j][r] - m_i);
    float ls = ((p[0][0] + p[0][1]) + (p[0][2] + p[0][3])) +
               ((p[1][0] + p[1][1]) + (p[1][2] + p[1][3])) +
               ((p[2][0] + p[2][1]) + (p[2][2] + p[2][3])) +
               ((p[3][0] + p[3][1]) + (p[3][2] + p[3][3]));
    ls += __shfl_xor(ls, 16);
    ls += __shfl_xor(ls, 32);
    l_i += ls;
    uint4 wA, wB;
    wA.x = pack2(p[0][0], p[0][1]); wA.y = pack2(p[0][2], p[0][3]);
    wA.z = pack2(p[1][0], p[1][1]); wA.w = pack2(p[1][2], p[1][3]);
    wB.x = pack2(p[2][0], p[2][1]); wB.y = pack2(p[2][2], p[2][3]);
    wB.z = pack2(p[3][0], p[3][1]); wB.w = pack2(p[3][2], p[3][3]);
    *(uint4*)&Pw[16 * g] = wA;
    *(uint4*)&Pw[16 * g + 8] = wB;

    // ---- barrier A: V(t) staged by all waves; K(t+1) stays in flight ----
    if (!lastk)
      asm volatile("s_waitcnt vmcnt(2)" ::: "memory");
    else
      asm volatile("s_waitcnt vmcnt(0)" ::: "memory");
    __builtin_amdgcn_s_barrier();
    asm volatile("" ::: "memory");

    // ---- PV (swapped): read P fragments, V from single buffer ----
    asm volatile("s_waitcnt lgkmcnt(0)" ::: "memory");
    const int S0 = 32 * (g & 1) + 4 * (g >> 1);
    uint2 a0 = *(const uint2*)&Pw[S0];
    uint2 a1 = *(const uint2*)&Pw[S0 + 16];
    uint2 b0 = *(const uint2*)&Pw[S0 + 8];
    uint2 b1 = *(const uint2*)&Pw[S0 + 24];
    uint4 u0; u0.x = a0.x; u0.y = a0.y; u0.z = a1.x; u0.w = a1.y;
    uint4 u1; u1.x = b0.x; u1.y = b0.y; u1.z = b1.x; u1.w = b1.y;
    bf16x8 pb0 = __builtin_bit_cast(bf16x8, u0);
    bf16x8 pb1 = __builtin_bit_cast(bf16x8, u1);
    __builtin_amdgcn_s_setprio(1);
#pragma unroll
    for (int c = 0; c < 8; ++c) {
      const int rvs = (c * 16 + cl) * 64;
      bf16x8 v0 = *(const bf16x8*)&Vsm[rvs + ((8 * g) ^ sw)];
      bf16x8 v1 = *(const bf16x8*)&Vsm[rvs + ((32 + 8 * g) ^ sw)];
      o[c] = __builtin_amdgcn_mfma_f32_16x16x32_bf16(v0, pb0, o[c], 0, 0, 0);
      o[c] = __builtin_amdgcn_mfma_f32_16x16x32_bf16(v1, pb1, o[c], 0, 0, 0);
    }
    __builtin_amdgcn_s_setprio(0);

    // ---- barrier B: K(t+1) landed; Vsm free for next stage ----
    asm volatile("s_waitcnt vmcnt(0)" ::: "memory");
    __builtin_amdgcn_s_barrier();
    asm volatile("" ::: "memory");
  }
#undef STAGEK
#undef STAGEV

  // ---- epilogue: transpose O^T -> O via per-wave LDS region ----
  short* Ol = SM + wave * 2176;  // 16 q-rows x 136 shorts
  const float invl = 1.0f / l_i;
#pragma unroll
  for (int c = 0; c < 8; ++c) {
    uint2 w;
    w.x = pack2(o[c][0] * invl, o[c][1] * invl);
    w.y = pack2(o[c][2] * invl, o[c][3] * invl);
    *(uint2*)&Ol[cl * 136 + c * 16 + 4 * g] = w;
  }
  asm volatile("s_waitcnt lgkmcnt(0)" ::: "memory");
  const int rowq = lane & 15, seg = lane >> 4;
  const short* srcl = Ol + rowq * 136 + seg * 32;
  short* dst = ao + (size_t)(b * 2048 + q0w + rowq) * 2048 + h * 128 + seg * 32;
#pragma unroll
  for (int k = 0; k < 4; ++k)
    *(bf16x8*)(dst + 8 * k) = *(const bf16x8*)(srcl + 8 * k);
}

extern "C" void kernel_launch(void* const* d_in, const int* in_sizes, int n_in,
                              void* d_out, int out_size, void* d_ws, size_t ws_size,
                              hipStream_t stream) {
  const float* x = (const float*)d_in[0];
  const float* Wq = (const float*)d_in[1];
  const float* Wk = (const float*)d_in[2];
  const float* Wv = (const float*)d_in[3];
  const float* Wo = (const float*)d_in[4];
  float* out = (float*)d_out;

  char* ws = (char*)d_ws;
  short* x_bf = (short*)ws;   ws += (size_t)4096 * 2048 * 2;
  short* wqkv_t = (short*)ws; ws += (size_t)3072 * 2048 * 2;
  short* wo_t = (short*)ws;   ws += (size_t)2048 * 2048 * 2;
  short* qkv = (short*)ws;    ws += (size_t)4096 * 3072 * 2;
  short* q_bf = (short*)ws;   ws += (size_t)2 * 16 * 2048 * 128 * 2;
  short* k_sel = (short*)ws;  ws += (size_t)2 * 4 * 1152 * 128 * 2;
  short* v_t = (short*)ws;    ws += (size_t)2 * 4 * 128 * 1152 * 2;
  short* ao = (short*)ws;     ws += (size_t)4096 * 2048 * 2;

  cvt_kernel<<<4096, 256, 0, stream>>>(x, x_bf, 1048576);
  transpose_all<<<dim3(160, 64), 256, 0, stream>>>(Wq, Wk, Wv, Wo, wqkv_t, wo_t);
  gemm_bt<1><<<dim3(24, 32), 256, 0, stream>>>(x_bf, wqkv_t, qkv, 4096, 3072, 2048);
  pp_kernel<<<25088, 256, 0, stream>>>(qkv, q_bf, k_sel, v_t);
  attn_kernel<<<512, 512, 0, stream>>>(q_bf, k_sel, v_t, ao);
  gemm_bt<0><<<dim3(16, 32), 256, 0, stream>>>(ao, wo_t, out, 4096, 2048, 2048);
}